// Round 13
// baseline (471.934 us; speedup 1.0000x reference)
//
#include <hip/hip_runtime.h>
#include <math.h>

// RegionalGNN: B=8192, NC=8, H=256, HD=1024, L=3.
// R13: R12 + amdgpu_waves_per_eu(1,2) on k_net. R12 failed because the LLVM
//      allocator targeted 4 waves/EU (128 VGPR) despite launch_bounds(512,1)
//      allowing 2 waves/EU, spilling ~30 regs -> 102MB scratch writes, 400us.
//      Pinning waves-per-eu gives a >=256-VGPR budget; peak live ~170 fits.
//      Everything else identical to R12 (2 A-tiles/wave, frag-packed weights).

typedef short bf16x8 __attribute__((ext_vector_type(8)));
typedef float f32x4  __attribute__((ext_vector_type(4)));

__device__ __forceinline__ float bflo(unsigned int u){ return __uint_as_float(u << 16); }
__device__ __forceinline__ float bfhi(unsigned int u){ return __uint_as_float(u & 0xffff0000u); }
__device__ __forceinline__ float bfs(short s){ return __uint_as_float((unsigned int)(unsigned short)s << 16); }
__device__ __forceinline__ unsigned short f2bf(float f){
  unsigned int u = __float_as_uint(f);
  u += 0x7fffu + ((u >> 16) & 1u);          // RNE
  return (unsigned short)(u >> 16);
}
__device__ __forceinline__ void unpack8(uint4 a, float* o){
  o[0]=bflo(a.x); o[1]=bfhi(a.x); o[2]=bflo(a.y); o[3]=bfhi(a.y);
  o[4]=bflo(a.z); o[5]=bfhi(a.z); o[6]=bflo(a.w); o[7]=bfhi(a.w);
}
__device__ __forceinline__ uint4 pack8(const float* v){
  uint4 r;
  r.x = (unsigned int)f2bf(v[0]) | ((unsigned int)f2bf(v[1]) << 16);
  r.y = (unsigned int)f2bf(v[2]) | ((unsigned int)f2bf(v[3]) << 16);
  r.z = (unsigned int)f2bf(v[4]) | ((unsigned int)f2bf(v[5]) << 16);
  r.w = (unsigned int)f2bf(v[6]) | ((unsigned int)f2bf(v[7]) << 16);
  return r;
}
__device__ __forceinline__ void gload16(const void* g, void* l){
  __builtin_amdgcn_global_load_lds(
      (const __attribute__((address_space(1))) unsigned int*)g,
      (__attribute__((address_space(3))) unsigned int*)l, 16, 0, 0);
}
__device__ __forceinline__ bf16x8 shfl8(bf16x8 v, int src){
  union U { bf16x8 h; int u[4]; };
  U a, r; a.h = v;
  #pragma unroll
  for (int j = 0; j < 4; j++) r.u[j] = __shfl(a.u[j], src);
  return r.h;
}
__device__ __forceinline__ bf16x8 pk8(const float* v){
  bf16x8 r;
  #pragma unroll
  for (int j = 0; j < 8; j++) r[j] = (short)f2bf(v[j]);
  return r;
}

// ---------------- convert f32 -> bf16 (Wq, Wk, Wv) ----------------
struct CvP { const float* src[4]; short* dst[4]; int boff[5]; };
__global__ __launch_bounds__(256) void k_convert(CvP p){
  int bid = blockIdx.x, s = 0;
  while (bid >= p.boff[s+1]) s++;
  size_t e = (size_t)(bid - p.boff[s]) * 2048 + (size_t)threadIdx.x * 8;
  const float* src = p.src[s] + e;
  float4 v0 = *(const float4*)src;
  float4 v1 = *(const float4*)(src + 4);
  float v[8] = {v0.x,v0.y,v0.z,v0.w,v1.x,v1.y,v1.z,v1.w};
  *(uint4*)(p.dst[s] + e) = pack8(v);
}

// ---------------- transpose + convert (Wi, Wo x3, Wp) ----------------
struct TrP { const float* src[5]; short* dst[5]; int rows[5]; int cols[5]; int toff[6]; };
__global__ __launch_bounds__(256) void k_transpose(TrP p){
  __shared__ float tile[64][65];
  int bid = blockIdx.x, s = 0;
  while (bid >= p.toff[s+1]) s++;
  int ti = bid - p.toff[s];
  int cols = p.cols[s], rows = p.rows[s];
  int ntc = cols >> 6;
  int r0 = (ti / ntc) * 64, c0 = (ti % ntc) * 64;
  const float* src = p.src[s];
  int row = threadIdx.x >> 2, jb = (threadIdx.x & 3) * 16;
  #pragma unroll
  for (int j = 0; j < 16; j += 4){
    float4 v = *(const float4*)(src + (size_t)(r0 + row) * cols + c0 + jb + j);
    tile[row][jb+j] = v.x; tile[row][jb+j+1] = v.y; tile[row][jb+j+2] = v.z; tile[row][jb+j+3] = v.w;
  }
  __syncthreads();
  short* dst = p.dst[s];
  float tmp[16];
  #pragma unroll
  for (int j = 0; j < 16; j++) tmp[j] = tile[jb + j][row];
  #pragma unroll
  for (int j = 0; j < 16; j += 8)
    *(uint4*)(dst + (size_t)(c0 + row) * rows + r0 + jb + j) = pack8(&tmp[j]);
}

// ---------------- bias-fold vectors via bf16 row-dots ----------------
__global__ __launch_bounds__(256) void k_vecs2(
    const short* Wqb, const short* Wkb, const short* WoTb,
    const float* bq, const float* bk, const float* bv, const float* bo,
    float* cq, float* ck, float* cvo, float* c0){
  const int job = blockIdx.x, l = blockIdx.y, tid = threadIdx.x;
  __shared__ float sv[1024];
  __shared__ float red[256];
  if (job == 3){
    float pp = 0.f;
    #pragma unroll
    for (int i = 0; i < 4; i++){
      int d = tid*4 + i;
      pp = fmaf(bq[l*1024 + d], bk[l*1024 + d], pp);
    }
    red[tid] = pp; __syncthreads();
    for (int o = 128; o > 0; o >>= 1){ if (tid < o) red[tid] += red[tid + o]; __syncthreads(); }
    if (tid == 0) c0[l] = red[0] * 0.0625f;
    return;
  }
  const short* rows = (job==0 ? Wqb : job==1 ? Wkb : WoTb) + (size_t)l*262144;
  const float* vecg = (job==0 ? bk : job==1 ? bq : bv) + l*1024;
  const float scale = (job == 2) ? 1.0f : 0.0625f;
  for (int i = tid; i < 1024; i += 256) sv[i] = vecg[i];
  __syncthreads();
  const int row = tid >> 3, sub = tid & 7;
  for (int pass = 0; pass < 8; pass++){
    int r = pass*32 + row;
    const short* rp = rows + (size_t)r*1024;
    float acc = 0.f;
    #pragma unroll
    for (int i = 0; i < 16; i++){
      int d = sub*8 + i*64;
      uint4 v = *(const uint4*)(rp + d);
      float f[8]; unpack8(v, f);
      #pragma unroll
      for (int j = 0; j < 8; j++) acc = fmaf(f[j], sv[d + j], acc);
    }
    acc += __shfl_xor(acc, 1); acc += __shfl_xor(acc, 2); acc += __shfl_xor(acc, 4);
    if (sub == 0){
      float o = acc * scale;
      if (job == 2) o += bo[l*256 + r];
      (job==0 ? cq : job==1 ? ck : cvo)[l*256 + r] = o;
    }
  }
}

// ---------------- 128x128 MFMA GEMM (weight precompute only) ----------------
struct GDesc { const short* A; const short* Bt; short* C; int K; float scale; };
struct GemmP { GDesc d[6]; };
__global__ __launch_bounds__(256) void k_gemm128(GemmP p){
  GDesc g = p.d[blockIdx.z];
  const int tid = threadIdx.x, lane = tid & 63, w = tid >> 6;
  const int wm = w >> 1, wn = w & 1;
  __shared__ alignas(16) short As[128*32];
  __shared__ alignas(16) short Bs[128*32];
  const int K = g.K;
  const short* Ab = g.A + (size_t)blockIdx.x * 128 * K;
  const short* Bb = g.Bt + (size_t)blockIdx.y * 128 * K;
  f32x4 acc[4][4] = {};
  for (int k0 = 0; k0 < K; k0 += 32){
    #pragma unroll
    for (int i = 0; i < 2; i++){
      int s = w*2 + i;
      int ro = (s >> 2)*64 + (s & 3)*16 + (lane & 15);
      int co = k0 + (lane >> 4) * 8;
      gload16(Ab + (size_t)ro * K + co, &As[s*512]);
      gload16(Bb + (size_t)ro * K + co, &Bs[s*512]);
    }
    __syncthreads();
    bf16x8 av[4], bv[4];
    #pragma unroll
    for (int mi = 0; mi < 4; mi++)
      av[mi] = *(const bf16x8*)&As[((wm*4 + mi)*64 + lane)*8];
    #pragma unroll
    for (int nj = 0; nj < 4; nj++)
      bv[nj] = *(const bf16x8*)&Bs[((wn*4 + nj)*64 + lane)*8];
    #pragma unroll
    for (int mi = 0; mi < 4; mi++)
      #pragma unroll
      for (int nj = 0; nj < 4; nj++)
        acc[mi][nj] = __builtin_amdgcn_mfma_f32_16x16x32_bf16(av[mi], bv[nj], acc[mi][nj], 0, 0, 0);
    __syncthreads();
  }
  const int ldc = gridDim.y * 128;
  #pragma unroll
  for (int mi = 0; mi < 4; mi++)
    #pragma unroll
    for (int nj = 0; nj < 4; nj++){
      int rm0 = blockIdx.x*128 + wm*64 + mi*16 + (lane >> 4) * 4;
      int cn  = blockIdx.y*128 + wn*64 + nj*16 + (lane & 15);
      #pragma unroll
      for (int j = 0; j < 4; j++)
        g.C[(size_t)(rm0 + j) * ldc + cn] = (short)f2bf(acc[mi][nj][j] * g.scale);
    }
}

// ---------------- frag-pack repack: row-major [N][K] -> [(K/32)*16][512] ----------------
struct RpP { const short* src[8]; short* dst[8]; int K[8]; int boff[9]; };
__global__ __launch_bounds__(256) void k_repack(RpP p){
  int bid = blockIdx.x, s = 0;
  while (bid >= p.boff[s+1]) s++;
  int kk = bid - p.boff[s];
  const short* src = p.src[s];
  short* dst = p.dst[s] + (size_t)kk * 8192;
  int K = p.K[s];
  int r15 = threadIdx.x & 15, nt = threadIdx.x >> 4;
  const short* sp = src + (size_t)(nt*16 + r15) * K + kk*32;
  short* dp = dst + nt*512 + r15*8;
  #pragma unroll
  for (int q = 0; q < 4; q++)
    *(uint4*)(dp + q*128) = *(const uint4*)(sp + q*8);
}

// ---------------- mega-kernel: whole network, 2 A-tiles per wave ----------------
// Block = 32 batches (256 X-rows), grid 256 = 1 block/CU. Wave owns tiles 2w,2w+1
// (rows w*32..w*32+31 = 4 batches). xf[t]: A-frag layout per tile. Stash of (r,d)
// for tile t in tst[w]: t*4096 + (d>>5)*512 + (r + 16*((d>>3)&3))*8 + (d&7).
__global__ __launch_bounds__(512)
__attribute__((amdgpu_waves_per_eu(1, 2)))
void k_net(
    const float* __restrict__ rf, const short* __restrict__ WiT,
    const float* __restrict__ bi, const float* __restrict__ emb,
    const short* __restrict__ Wqk, const short* __restrict__ Wvo,
    const float* __restrict__ ckv, const float* __restrict__ cvov,
    const float* __restrict__ lng, const float* __restrict__ lnb,
    const short* __restrict__ WpT, const float* __restrict__ bpv,
    const float* __restrict__ lpg, const float* __restrict__ lpb,
    float* __restrict__ outp){
  const int tid = threadIdx.x, lane = tid & 63, w = tid >> 6;
  const int b0 = blockIdx.x * 32;                 // batch base
  const int dsub = (lane >> 4) * 8;
  __shared__ alignas(16) short tst[8][8192];      // 128 KB: per-wave 16KB stash (2 tiles)
  __shared__ alignas(16) float atn[8][2][16][16]; // 16 KB
  __shared__ short ckb[256];
  __shared__ float s_add[256], s_g[256], s_b[256];
  __shared__ float redS[8][32], redQ[8][32], s_mean[32], s_rstd[32];

  #define LKW asm volatile("s_waitcnt lgkmcnt(0)" ::: "memory")

  // ===== input projection: h = rf@Wi + bi (B frag-packed, shared by 2 tiles) =====
  float* hst  = (float*)&tst[0][0];   // [32][264] f32
  float* embs = hst + 32*264;         // [8][256]  f32
  float* bis  = embs + 2048;          // [256]     f32
  if (tid < 256) bis[tid] = bi[tid];
  for (int i = tid; i < 2048; i += 512) embs[i] = emb[i];
  f32x4 hacc[2][2] = {};
  #pragma unroll
  for (int kk = 0; kk < 16; kk++){
    bf16x8 bvv[2];
    #pragma unroll
    for (int nj = 0; nj < 2; nj++)
      bvv[nj] = *(const bf16x8*)(WiT + (size_t)(kk*16 + w*2 + nj)*512 + lane*8);
    #pragma unroll
    for (int u = 0; u < 2; u++){
      const float* ap = rf + (size_t)(b0 + u*16 + (lane & 15)) * 512 + kk*32 + dsub;
      float4 a0 = *(const float4*)ap, a1 = *(const float4*)(ap + 4);
      float af[8] = {a0.x,a0.y,a0.z,a0.w,a1.x,a1.y,a1.z,a1.w};
      bf16x8 av = pk8(af);
      #pragma unroll
      for (int nj = 0; nj < 2; nj++)
        hacc[u][nj] = __builtin_amdgcn_mfma_f32_16x16x32_bf16(av, bvv[nj], hacc[u][nj], 0, 0, 0);
    }
  }
  __syncthreads();   // bis/embs published
  #pragma unroll
  for (int u = 0; u < 2; u++)
    #pragma unroll
    for (int nj = 0; nj < 2; nj++)
      #pragma unroll
      for (int jj = 0; jj < 4; jj++){
        int m = u*16 + (lane >> 4)*4 + jj, col = w*32 + nj*16 + (lane & 15);
        hst[m*264 + col] = hacc[u][nj][jj] + bis[col];
      }
  __syncthreads();   // hst published
  // build xf[t] (A-layout) = bf16(h + bi + emb); tile t rows = w*32 + t*16 + r15
  bf16x8 xf[2][8];
  {
    int r15 = lane & 15, ct = r15 & 7;
    #pragma unroll
    for (int t = 0; t < 2; t++){
      int bt = w*4 + t*2 + (r15 >> 3);
      #pragma unroll
      for (int c = 0; c < 8; c++){
        float v8[8];
        #pragma unroll
        for (int e = 0; e < 8; e++){
          int d = dsub + 32*c + e;
          v8[e] = hst[bt*264 + d] + embs[ct*256 + d];
        }
        xf[t][c] = pk8(v8);
      }
    }
  }

  const unsigned long long MASK64 = 0x02191D69752B857EULL;   // ADJ[n][m] at bit n*8+m

  // ===== layers =====
  #pragma unroll 1
  for (int l = 0; l < 3; ++l){
    __syncthreads();   // protect hst readers (l==0) / prev-layer s_* readers
    if (tid < 256){
      ckb[tid]   = (short)f2bf(ckv[l*256 + tid]);
      s_add[tid] = cvov[l*256 + tid];
      s_g[tid]   = lng[l*256 + tid];
      s_b[tid]   = lnb[l*256 + tid];
    }
    const short* Wq_ = Wqk + l*65536;   // frag-packed [8 kk][16 ntile][512]
    const short* Wv_ = Wvo + l*65536;
    __syncthreads();   // publish

    // ---- GEMM1: T = X @ Wqk; each B-load feeds both tiles; scores via stash-MFMA ----
    f32x4 sacc[2] = {};
    #pragma unroll
    for (int h = 0; h < 2; h++){
      f32x4 acc[2][8] = {};
      #pragma unroll
      for (int kk = 0; kk < 8; kk++)
        #pragma unroll
        for (int nj = 0; nj < 8; nj++){
          bf16x8 bv = *(const bf16x8*)(Wq_ + (size_t)(kk*16 + h*8 + nj)*512 + lane*8);
          acc[0][nj] = __builtin_amdgcn_mfma_f32_16x16x32_bf16(xf[0][kk], bv, acc[0][nj], 0, 0, 0);
          acc[1][nj] = __builtin_amdgcn_mfma_f32_16x16x32_bf16(xf[1][kk], bv, acc[1][nj], 0, 0, 0);
        }
      #pragma unroll
      for (int t = 0; t < 2; t++)
        #pragma unroll
        for (int nj = 0; nj < 8; nj++)
          #pragma unroll
          for (int jj = 0; jj < 4; jj++){
            int i_ = (lane >> 4)*4 + jj, nl = nj*16 + (lane & 15);
            tst[w][t*4096 + (nl >> 5)*512 + (i_ + 16*((nl >> 3) & 3))*8 + (nl & 7)]
                = (short)f2bf(acc[t][nj][jj]);
          }
      LKW; __builtin_amdgcn_sched_barrier(0);
      #pragma unroll
      for (int t = 0; t < 2; t++)
        #pragma unroll
        for (int cl = 0; cl < 4; cl++){
          bf16x8 tf = *(const bf16x8*)&tst[w][t*4096 + cl*512 + lane*8];
          sacc[t] = __builtin_amdgcn_mfma_f32_16x16x32_bf16(tf, xf[t][h*4 + cl], sacc[t], 0, 0, 0);
        }
      LKW;   // reads drained before next-half overwrite
    }

    // ---- skv[t][m] = X[m].ck ----
    float skv[2];
    #pragma unroll
    for (int t = 0; t < 2; t++){
      float sv_ = 0.f;
      #pragma unroll
      for (int c = 0; c < 8; c++){
        bf16x8 cv = *(const bf16x8*)&ckb[c*32 + dsub];
        #pragma unroll
        for (int e = 0; e < 8; e++) sv_ = fmaf(bfs(xf[t][c][e]), bfs(cv[e]), sv_);
      }
      sv_ += __shfl_xor(sv_, 16); sv_ += __shfl_xor(sv_, 32);
      skv[t] = sv_;
    }

    // ---- softmax (C-layout) -> atn[w][t] ----
    #pragma unroll
    for (int t = 0; t < 2; t++)
      #pragma unroll
      for (int jj = 0; jj < 4; jj++){
        int i_ = (lane >> 4)*4 + jj, j_ = lane & 15;
        bool ok = (((i_ ^ j_) & 8) == 0) &&
                  ((MASK64 >> (((i_ & 7) << 3) | (j_ & 7))) & 1ull);
        float sv = ok ? (sacc[t][jj] + skv[t]) : -3.0e38f;
        float mx = sv;
        mx = fmaxf(mx, __shfl_xor(mx, 1));
        mx = fmaxf(mx, __shfl_xor(mx, 2));
        mx = fmaxf(mx, __shfl_xor(mx, 4));
        float e = ok ? __expf(sv - mx) : 0.f;
        float sum = e;
        sum += __shfl_xor(sum, 1); sum += __shfl_xor(sum, 2); sum += __shfl_xor(sum, 4);
        atn[w][t][i_][j_] = e / sum;
      }
    LKW;   // own-wave atn writes -> reads

    // ---- PV: yfrag[t] (A-layout) via shfl from xf[t] ----
    bf16x8 yfrag[2][8];
    #pragma unroll
    for (int t = 0; t < 2; t++){
      float4 A0 = *(const float4*)&atn[w][t][lane & 15][lane & 8];
      float4 A1 = *(const float4*)&atn[w][t][lane & 15][(lane & 8) + 4];
      float am[8] = {A0.x, A0.y, A0.z, A0.w, A1.x, A1.y, A1.z, A1.w};
      #pragma unroll
      for (int c = 0; c < 8; c++){
        float a8[8] = {0,0,0,0,0,0,0,0};
        #pragma unroll
        for (int mi = 0; mi < 8; mi++){
          bf16x8 xs = shfl8(xf[t][c], (lane & 48) | (lane & 8) | mi);
          #pragma unroll
          for (int e = 0; e < 8; e++) a8[e] = fmaf(am[mi], bfs(xs[e]), a8[e]);
        }
        yfrag[t][c] = pk8(a8);
      }
    }

    // ---- stash X (A-layout, contiguous b128) -> tst[w]; xf dead until LN-apply ----
    #pragma unroll
    for (int t = 0; t < 2; t++)
      #pragma unroll
      for (int c = 0; c < 8; c++)
        *(bf16x8*)&tst[w][t*4096 + c*512 + lane*8] = xf[t][c];
    LKW; __builtin_amdgcn_sched_barrier(0);

    // ---- GEMM2 + epilogue: t = acc + cvo + X_res (from stash, C-layout) ----
    float rs[2][4] = {}, rq[2][4] = {};
    #pragma unroll
    for (int h = 0; h < 2; h++){
      f32x4 acc[2][8] = {};
      #pragma unroll
      for (int kk = 0; kk < 8; kk++)
        #pragma unroll
        for (int nj = 0; nj < 8; nj++){
          bf16x8 bv = *(const bf16x8*)(Wv_ + (size_t)(kk*16 + h*8 + nj)*512 + lane*8);
          acc[0][nj] = __builtin_amdgcn_mfma_f32_16x16x32_bf16(yfrag[0][kk], bv, acc[0][nj], 0, 0, 0);
          acc[1][nj] = __builtin_amdgcn_mfma_f32_16x16x32_bf16(yfrag[1][kk], bv, acc[1][nj], 0, 0, 0);
        }
      #pragma unroll
      for (int t = 0; t < 2; t++)
        #pragma unroll
        for (int nj = 0; nj < 8; nj++){
          int n = h*128 + nj*16 + (lane & 15);
          float sadd = s_add[n];
          #pragma unroll
          for (int jj = 0; jj < 4; jj++){
            int i_ = (lane >> 4)*4 + jj;
            int ad = t*4096 + (n >> 5)*512 + (i_ + 16*((n >> 3) & 3))*8 + (n & 7);
            float tv = acc[t][nj][jj] + sadd + bfs(tst[w][ad]);  // RAW same-lane
            rs[t][jj] += tv; rq[t][jj] = fmaf(tv, tv, rq[t][jj]);
            tst[w][ad] = (short)f2bf(tv);
          }
        }
    }
    // ---- LN stats -> atn[w][t] scratch (attn probs dead) ----
    #pragma unroll
    for (int t = 0; t < 2; t++){
      float* stp = &atn[w][t][0][0];
      #pragma unroll
      for (int jj = 0; jj < 4; jj++){
        float s = rs[t][jj], q = rq[t][jj];
        s += __shfl_xor(s, 1); q += __shfl_xor(q, 1);
        s += __shfl_xor(s, 2); q += __shfl_xor(q, 2);
        s += __shfl_xor(s, 4); q += __shfl_xor(q, 4);
        s += __shfl_xor(s, 8); q += __shfl_xor(q, 8);
        if ((lane & 15) == 0){
          int i_ = (lane >> 4)*4 + jj;
          float mn = s * (1.f/256.f);
          float var = q * (1.f/256.f) - mn*mn;
          stp[i_]      = mn;
          stp[16 + i_] = rsqrtf(fmaxf(var, 0.f) + 1e-5f);
        }
      }
    }
    LKW; __builtin_amdgcn_sched_barrier(0);   // t-writes + stp visible within wave
    // ---- LN apply: read t (A-layout contiguous), row stats = row lane&15 ----
    #pragma unroll
    for (int t = 0; t < 2; t++){
      float* stp = &atn[w][t][0][0];
      float mn = stp[lane & 15], rr = stp[16 + (lane & 15)];
      #pragma unroll
      for (int c = 0; c < 8; c++){
        bf16x8 tv = *(const bf16x8*)&tst[w][t*4096 + c*512 + lane*8];
        float v8[8];
        #pragma unroll
        for (int e = 0; e < 8; e++){
          int d = c*32 + dsub + e;
          v8[e] = (bfs(tv[e]) - mn) * rr * s_g[d] + s_b[d];
        }
        xf[t][c] = pk8(v8);
      }
    }
    LKW;   // stash reads drained before next layer reuses tst[w]
  } // layers

  // ===== head: GDP-reduce -> Astage -> GEMM vs frag-packed WpT -> LN -> GELU =====
  __syncthreads();   // tst becomes cross-wave Astage
  short* Ast = &tst[0][0];   // [32][264] bf16
  {
    int c7 = lane & 7;
    float g = (c7 == 0) ? 0.4f : (c7 == 1) ? 0.15f : (c7 == 2) ? 0.12f :
              (c7 == 3) ? 0.1f : (c7 == 4) ? 0.08f : (c7 == 5) ? 0.08f :
              (c7 == 6) ? 0.05f : 0.02f;
    #pragma unroll
    for (int t = 0; t < 2; t++)
      #pragma unroll
      for (int c = 0; c < 8; c++){
        float v8[8];
        #pragma unroll
        for (int e = 0; e < 8; e++){
          float v = g * bfs(xf[t][c][e]);
          v += __shfl_xor(v, 1); v += __shfl_xor(v, 2); v += __shfl_xor(v, 4);
          v8[e] = v;
        }
        if ((lane & 7) == 0){
          int bt = w*4 + t*2 + ((lane >> 3) & 1);
          *(bf16x8*)&Ast[bt*264 + dsub + 32*c] = pk8(v8);
        }
      }
  }
  __syncthreads();
  f32x4 ha[2][2] = {};
  #pragma unroll
  for (int kk = 0; kk < 8; kk++){
    bf16x8 bvv[2];
    #pragma unroll
    for (int nj = 0; nj < 2; nj++)
      bvv[nj] = *(const bf16x8*)(WpT + (size_t)(kk*16 + w*2 + nj)*512 + lane*8);
    #pragma unroll
    for (int u = 0; u < 2; u++){
      bf16x8 av = *(const bf16x8*)&Ast[(u*16 + (lane & 15))*264 + kk*32 + dsub];
      #pragma unroll
      for (int nj = 0; nj < 2; nj++)
        ha[u][nj] = __builtin_amdgcn_mfma_f32_16x16x32_bf16(av, bvv[nj], ha[u][nj], 0, 0, 0);
    }
  }
  #pragma unroll
  for (int u = 0; u < 2; u++)
    #pragma unroll
    for (int jj = 0; jj < 4; jj++){
      float s = 0.f, q = 0.f;
      #pragma unroll
      for (int nj = 0; nj < 2; nj++){
        int cx = w*32 + nj*16 + (lane & 15);
        float t = ha[u][nj][jj] + bpv[cx];
        ha[u][nj][jj] = t;
        s += t; q = fmaf(t, t, q);
      }
      s += __shfl_xor(s, 1); q += __shfl_xor(q, 1);
      s += __shfl_xor(s, 2); q += __shfl_xor(q, 2);
      s += __shfl_xor(s, 4); q += __shfl_xor(q, 4);
      s += __shfl_xor(s, 8); q += __shfl_xor(q, 8);
      if ((lane & 15) == 0){
        int rl = u*16 + (lane >> 4)*4 + jj;
        redS[w][rl] = s; redQ[w][rl] = q;
      }
    }
  __syncthreads();
  if (tid < 32){
    float sm = 0.f, sq = 0.f;
    #pragma unroll
    for (int w2 = 0; w2 < 8; w2++){ sm += redS[w2][tid]; sq += redQ[w2][tid]; }
    float mn = sm * (1.f/256.f);
    float var = sq * (1.f/256.f) - mn*mn;
    s_mean[tid] = mn;
    s_rstd[tid] = rsqrtf(fmaxf(var, 0.f) + 1e-5f);
  }
  __syncthreads();
  #pragma unroll
  for (int u = 0; u < 2; u++)
    #pragma unroll
    for (int jj = 0; jj < 4; jj++){
      int rl = u*16 + (lane >> 4)*4 + jj;
      float mn = s_mean[rl], rstd = s_rstd[rl];
      #pragma unroll
      for (int nj = 0; nj < 2; nj++){
        int cx = w*32 + nj*16 + (lane & 15);
        float y = (ha[u][nj][jj] - mn) * rstd * lpg[cx] + lpb[cx];
        outp[(size_t)(b0 + rl)*256 + cx] = 0.5f * y * (1.0f + erff(y * 0.70710678118654752f));
      }
    }
  #undef LKW
}

extern "C" void kernel_launch(void* const* d_in, const int* in_sizes, int n_in,
                              void* d_out, int out_size, void* d_ws, size_t ws_size,
                              hipStream_t stream){
  (void)in_sizes; (void)n_in; (void)out_size; (void)ws_size;
  const float* rf  = (const float*)d_in[0];
  const float* Wi  = (const float*)d_in[1];
  const float* bi  = (const float*)d_in[2];
  const float* emb = (const float*)d_in[3];
  const float* Wq  = (const float*)d_in[4];
  const float* bq  = (const float*)d_in[5];
  const float* Wk  = (const float*)d_in[6];
  const float* bk  = (const float*)d_in[7];
  const float* Wv  = (const float*)d_in[8];
  const float* bv  = (const float*)d_in[9];
  const float* Wo  = (const float*)d_in[10];
  const float* bo  = (const float*)d_in[11];
  const float* lng = (const float*)d_in[12];
  const float* lnb = (const float*)d_in[13];
  const float* Wp  = (const float*)d_in[14];
  const float* bp  = (const float*)d_in[15];
  const float* lpg = (const float*)d_in[16];
  const float* lpb = (const float*)d_in[17];

  char* ws = (char*)d_ws;
  short* Wqb  = (short*)(ws);                      // [3][256][1024] bf16
  short* Wkb  = (short*)(ws + 1572864ull);
  short* Wvb  = (short*)(ws + 3145728ull);
  short* WoTb = (short*)(ws + 4718592ull);         // [3][256][1024]
  short* WiTb = (short*)(ws + 6291456ull);         // [256][512] row-major
  short* WpTb = (short*)(ws + 6553600ull);         // [256][256] row-major
  short* Wqk  = (short*)(ws + 6684672ull);         // [3][256][256] row-major, pre-scaled 1/16
  short* Wvo  = (short*)(ws + 7077888ull);         // [3][256][256] row-major
  float* cqv  = (float*)(ws + 7471104ull);
  float* ckv  = (float*)(ws + 7474176ull);
  float* cvov = (float*)(ws + 7477248ull);
  float* c0v  = (float*)(ws + 7480320ull);
  // frag-packed copies
  short* WqkP = (short*)(ws + 7483392ull);         // [3][8][16][512]
  short* WvoP = (short*)(ws + 7876608ull);         // [3][8][16][512]
  short* WiTP = (short*)(ws + 8269824ull);         // [16][16][512]
  short* WpTP = (short*)(ws + 8531968ull);         // [8][16][512]

  { CvP cv;
    cv.src[0]=Wq; cv.dst[0]=Wqb;
    cv.src[1]=Wk; cv.dst[1]=Wkb;
    cv.src[2]=Wv; cv.dst[2]=Wvb;
    cv.src[3]=Wv; cv.dst[3]=Wvb;   // unused slot
    cv.boff[0]=0; cv.boff[1]=384; cv.boff[2]=768; cv.boff[3]=1152; cv.boff[4]=1152;
    k_convert<<<dim3(1152), dim3(256), 0, stream>>>(cv); }

  { TrP tp;
    tp.src[0]=Wi;          tp.dst[0]=WiTb;          tp.rows[0]=512;  tp.cols[0]=256;
    tp.src[1]=Wo;          tp.dst[1]=WoTb;          tp.rows[1]=1024; tp.cols[1]=256;
    tp.src[2]=Wo+262144;   tp.dst[2]=WoTb+262144;   tp.rows[2]=1024; tp.cols[2]=256;
    tp.src[3]=Wo+524288;   tp.dst[3]=WoTb+524288;   tp.rows[3]=1024; tp.cols[3]=256;
    tp.src[4]=Wp;          tp.dst[4]=WpTb;          tp.rows[4]=256;  tp.cols[4]=256;
    tp.toff[0]=0; tp.toff[1]=32; tp.toff[2]=96; tp.toff[3]=160; tp.toff[4]=224; tp.toff[5]=240;
    k_transpose<<<dim3(240), dim3(256), 0, stream>>>(tp); }

  k_vecs2<<<dim3(4, 3), dim3(256), 0, stream>>>(Wqb, Wkb, WoTb, bq, bk, bv, bo,
                                                cqv, ckv, cvov, c0v);

  { GemmP g{};
    for (int l = 0; l < 3; l++){
      g.d[l]   = GDesc{ Wkb  + l*262144, Wqb + l*262144, Wqk + l*65536, 1024, 0.0625f };
      g.d[3+l] = GDesc{ WoTb + l*262144, Wvb + l*262144, Wvo + l*65536, 1024, 1.0f };
    }
    k_gemm128<<<dim3(2,2,6), dim3(256), 0, stream>>>(g); }

  { RpP rp;
    for (int l = 0; l < 3; l++){
      rp.src[l]   = Wqk + l*65536; rp.dst[l]   = WqkP + l*65536; rp.K[l]   = 256;
      rp.src[3+l] = Wvo + l*65536; rp.dst[3+l] = WvoP + l*65536; rp.K[3+l] = 256;
    }
    rp.src[6] = WiTb; rp.dst[6] = WiTP; rp.K[6] = 512;
    rp.src[7] = WpTb; rp.dst[7] = WpTP; rp.K[7] = 256;
    rp.boff[0]=0; rp.boff[1]=8; rp.boff[2]=16; rp.boff[3]=24; rp.boff[4]=32;
    rp.boff[5]=40; rp.boff[6]=48; rp.boff[7]=64; rp.boff[8]=72;
    k_repack<<<dim3(72), dim3(256), 0, stream>>>(rp); }

  k_net<<<dim3(256), dim3(512), 0, stream>>>(rf, WiTP, bi, emb, WqkP, WvoP,
      ckv, cvov, lng, lnb, WpTP, bp, lpg, lpb, (float*)d_out);
}

// Round 14
// 264.347 us; speedup vs baseline: 1.7853x; 1.7853x over previous
//
#include <hip/hip_runtime.h>
#include <math.h>

// RegionalGNN: B=8192, NC=8, H=256, HD=1024, L=3.
// R14: base = R11 (best: k_net 250us, VGPR 116 no-spill). Change: weights staged
//      per-BLOCK into LDS via global_load_lds (zero VGPR cost; frag-packed layout
//      makes it a linear copy), B-frags via conflict-free lane-linear ds_read_b128.
//      Per-CU weight traffic 16x-per-wave -> 1x-per-block; kills the L2-latency-
//      bound load pipeline R11 stalled on. Staging overlapped with PV/epilogue.
//      (R12/R13 lesson: allocator hard-caps 128 VGPR; 2-tile/wave is infeasible.)

typedef short bf16x8 __attribute__((ext_vector_type(8)));
typedef float f32x4  __attribute__((ext_vector_type(4)));

__device__ __forceinline__ float bflo(unsigned int u){ return __uint_as_float(u << 16); }
__device__ __forceinline__ float bfhi(unsigned int u){ return __uint_as_float(u & 0xffff0000u); }
__device__ __forceinline__ float bfs(short s){ return __uint_as_float((unsigned int)(unsigned short)s << 16); }
__device__ __forceinline__ unsigned short f2bf(float f){
  unsigned int u = __float_as_uint(f);
  u += 0x7fffu + ((u >> 16) & 1u);          // RNE
  return (unsigned short)(u >> 16);
}
__device__ __forceinline__ void unpack8(uint4 a, float* o){
  o[0]=bflo(a.x); o[1]=bfhi(a.x); o[2]=bflo(a.y); o[3]=bfhi(a.y);
  o[4]=bflo(a.z); o[5]=bfhi(a.z); o[6]=bflo(a.w); o[7]=bfhi(a.w);
}
__device__ __forceinline__ uint4 pack8(const float* v){
  uint4 r;
  r.x = (unsigned int)f2bf(v[0]) | ((unsigned int)f2bf(v[1]) << 16);
  r.y = (unsigned int)f2bf(v[2]) | ((unsigned int)f2bf(v[3]) << 16);
  r.z = (unsigned int)f2bf(v[4]) | ((unsigned int)f2bf(v[5]) << 16);
  r.w = (unsigned int)f2bf(v[6]) | ((unsigned int)f2bf(v[7]) << 16);
  return r;
}
__device__ __forceinline__ void gload16(const void* g, void* l){
  __builtin_amdgcn_global_load_lds(
      (const __attribute__((address_space(1))) unsigned int*)g,
      (__attribute__((address_space(3))) unsigned int*)l, 16, 0, 0);
}
__device__ __forceinline__ bf16x8 shfl8(bf16x8 v, int src){
  union U { bf16x8 h; int u[4]; };
  U a, r; a.h = v;
  #pragma unroll
  for (int j = 0; j < 4; j++) r.u[j] = __shfl(a.u[j], src);
  return r.h;
}
__device__ __forceinline__ bf16x8 pk8(const float* v){
  bf16x8 r;
  #pragma unroll
  for (int j = 0; j < 8; j++) r[j] = (short)f2bf(v[j]);
  return r;
}

// ---------------- convert f32 -> bf16 (Wq, Wk, Wv) ----------------
struct CvP { const float* src[4]; short* dst[4]; int boff[5]; };
__global__ __launch_bounds__(256) void k_convert(CvP p){
  int bid = blockIdx.x, s = 0;
  while (bid >= p.boff[s+1]) s++;
  size_t e = (size_t)(bid - p.boff[s]) * 2048 + (size_t)threadIdx.x * 8;
  const float* src = p.src[s] + e;
  float4 v0 = *(const float4*)src;
  float4 v1 = *(const float4*)(src + 4);
  float v[8] = {v0.x,v0.y,v0.z,v0.w,v1.x,v1.y,v1.z,v1.w};
  *(uint4*)(p.dst[s] + e) = pack8(v);
}

// ---------------- transpose + convert (Wi, Wo x3, Wp) ----------------
struct TrP { const float* src[5]; short* dst[5]; int rows[5]; int cols[5]; int toff[6]; };
__global__ __launch_bounds__(256) void k_transpose(TrP p){
  __shared__ float tile[64][65];
  int bid = blockIdx.x, s = 0;
  while (bid >= p.toff[s+1]) s++;
  int ti = bid - p.toff[s];
  int cols = p.cols[s], rows = p.rows[s];
  int ntc = cols >> 6;
  int r0 = (ti / ntc) * 64, c0 = (ti % ntc) * 64;
  const float* src = p.src[s];
  int row = threadIdx.x >> 2, jb = (threadIdx.x & 3) * 16;
  #pragma unroll
  for (int j = 0; j < 16; j += 4){
    float4 v = *(const float4*)(src + (size_t)(r0 + row) * cols + c0 + jb + j);
    tile[row][jb+j] = v.x; tile[row][jb+j+1] = v.y; tile[row][jb+j+2] = v.z; tile[row][jb+j+3] = v.w;
  }
  __syncthreads();
  short* dst = p.dst[s];
  float tmp[16];
  #pragma unroll
  for (int j = 0; j < 16; j++) tmp[j] = tile[jb + j][row];
  #pragma unroll
  for (int j = 0; j < 16; j += 8)
    *(uint4*)(dst + (size_t)(c0 + row) * rows + r0 + jb + j) = pack8(&tmp[j]);
}

// ---------------- bias-fold vectors via bf16 row-dots ----------------
__global__ __launch_bounds__(256) void k_vecs2(
    const short* Wqb, const short* Wkb, const short* WoTb,
    const float* bq, const float* bk, const float* bv, const float* bo,
    float* cq, float* ck, float* cvo, float* c0){
  const int job = blockIdx.x, l = blockIdx.y, tid = threadIdx.x;
  __shared__ float sv[1024];
  __shared__ float red[256];
  if (job == 3){
    float pp = 0.f;
    #pragma unroll
    for (int i = 0; i < 4; i++){
      int d = tid*4 + i;
      pp = fmaf(bq[l*1024 + d], bk[l*1024 + d], pp);
    }
    red[tid] = pp; __syncthreads();
    for (int o = 128; o > 0; o >>= 1){ if (tid < o) red[tid] += red[tid + o]; __syncthreads(); }
    if (tid == 0) c0[l] = red[0] * 0.0625f;
    return;
  }
  const short* rows = (job==0 ? Wqb : job==1 ? Wkb : WoTb) + (size_t)l*262144;
  const float* vecg = (job==0 ? bk : job==1 ? bq : bv) + l*1024;
  const float scale = (job == 2) ? 1.0f : 0.0625f;
  for (int i = tid; i < 1024; i += 256) sv[i] = vecg[i];
  __syncthreads();
  const int row = tid >> 3, sub = tid & 7;
  for (int pass = 0; pass < 8; pass++){
    int r = pass*32 + row;
    const short* rp = rows + (size_t)r*1024;
    float acc = 0.f;
    #pragma unroll
    for (int i = 0; i < 16; i++){
      int d = sub*8 + i*64;
      uint4 v = *(const uint4*)(rp + d);
      float f[8]; unpack8(v, f);
      #pragma unroll
      for (int j = 0; j < 8; j++) acc = fmaf(f[j], sv[d + j], acc);
    }
    acc += __shfl_xor(acc, 1); acc += __shfl_xor(acc, 2); acc += __shfl_xor(acc, 4);
    if (sub == 0){
      float o = acc * scale;
      if (job == 2) o += bo[l*256 + r];
      (job==0 ? cq : job==1 ? ck : cvo)[l*256 + r] = o;
    }
  }
}

// ---------------- 128x128 MFMA GEMM (weight precompute only) ----------------
struct GDesc { const short* A; const short* Bt; short* C; int K; float scale; };
struct GemmP { GDesc d[6]; };
__global__ __launch_bounds__(256) void k_gemm128(GemmP p){
  GDesc g = p.d[blockIdx.z];
  const int tid = threadIdx.x, lane = tid & 63, w = tid >> 6;
  const int wm = w >> 1, wn = w & 1;
  __shared__ alignas(16) short As[128*32];
  __shared__ alignas(16) short Bs[128*32];
  const int K = g.K;
  const short* Ab = g.A + (size_t)blockIdx.x * 128 * K;
  const short* Bb = g.Bt + (size_t)blockIdx.y * 128 * K;
  f32x4 acc[4][4] = {};
  for (int k0 = 0; k0 < K; k0 += 32){
    #pragma unroll
    for (int i = 0; i < 2; i++){
      int s = w*2 + i;
      int ro = (s >> 2)*64 + (s & 3)*16 + (lane & 15);
      int co = k0 + (lane >> 4) * 8;
      gload16(Ab + (size_t)ro * K + co, &As[s*512]);
      gload16(Bb + (size_t)ro * K + co, &Bs[s*512]);
    }
    __syncthreads();
    bf16x8 av[4], bv[4];
    #pragma unroll
    for (int mi = 0; mi < 4; mi++)
      av[mi] = *(const bf16x8*)&As[((wm*4 + mi)*64 + lane)*8];
    #pragma unroll
    for (int nj = 0; nj < 4; nj++)
      bv[nj] = *(const bf16x8*)&Bs[((wn*4 + nj)*64 + lane)*8];
    #pragma unroll
    for (int mi = 0; mi < 4; mi++)
      #pragma unroll
      for (int nj = 0; nj < 4; nj++)
        acc[mi][nj] = __builtin_amdgcn_mfma_f32_16x16x32_bf16(av[mi], bv[nj], acc[mi][nj], 0, 0, 0);
    __syncthreads();
  }
  const int ldc = gridDim.y * 128;
  #pragma unroll
  for (int mi = 0; mi < 4; mi++)
    #pragma unroll
    for (int nj = 0; nj < 4; nj++){
      int rm0 = blockIdx.x*128 + wm*64 + mi*16 + (lane >> 4) * 4;
      int cn  = blockIdx.y*128 + wn*64 + nj*16 + (lane & 15);
      #pragma unroll
      for (int j = 0; j < 4; j++)
        g.C[(size_t)(rm0 + j) * ldc + cn] = (short)f2bf(acc[mi][nj][j] * g.scale);
    }
}

// ---------------- frag-pack repack: row-major [N][K] -> [(K/32)*16][512] ----------------
struct RpP { const short* src[8]; short* dst[8]; int K[8]; int boff[9]; };
__global__ __launch_bounds__(256) void k_repack(RpP p){
  int bid = blockIdx.x, s = 0;
  while (bid >= p.boff[s+1]) s++;
  int kk = bid - p.boff[s];
  const short* src = p.src[s];
  short* dst = p.dst[s] + (size_t)kk * 8192;
  int K = p.K[s];
  int r15 = threadIdx.x & 15, nt = threadIdx.x >> 4;
  const short* sp = src + (size_t)(nt*16 + r15) * K + kk*32;
  short* dp = dst + nt*512 + r15*8;
  #pragma unroll
  for (int q = 0; q < 4; q++)
    *(uint4*)(dp + q*128) = *(const uint4*)(sp + q*8);
}

// ---------------- mega-kernel: whole network, X in registers, LDS-staged weights ----------------
// Block = 16 batches (128 X-rows), 8 waves. Wave = batch-pair (lane&15 = row).
// xf: A-frag layout. Stash of (r,d) in tst[w]: (d>>5)*512 + (r + 16*((d>>3)&3))*8 + (d&7).
// Weight halves (64KB = 8kk x 8nj x 1KB) staged block-wide into wbuf via
// global_load_lds (wave w stages chunk kk=w); B-frags = lane-linear ds_read_b128.
__global__ __launch_bounds__(512, 2) void k_net(
    const float* __restrict__ rf, const short* __restrict__ WiT,
    const float* __restrict__ bi, const float* __restrict__ emb,
    const short* __restrict__ Wqk, const short* __restrict__ Wvo,
    const float* __restrict__ ckv, const float* __restrict__ cvov,
    const float* __restrict__ lng, const float* __restrict__ lnb,
    const short* __restrict__ WpT, const float* __restrict__ bpv,
    const float* __restrict__ lpg, const float* __restrict__ lpb,
    float* __restrict__ outp){
  const int tid = threadIdx.x, lane = tid & 63, w = tid >> 6;
  const int b0 = blockIdx.x * 16;
  const int dsub = (lane >> 4) * 8;
  __shared__ alignas(16) short tst[8][4096];     // 64 KB: per-wave 8KB stash
  __shared__ alignas(16) short wbuf[32768];      // 64 KB: one weight half
  __shared__ alignas(16) float atn[8][16][16];   // 8 KB
  __shared__ short ckb[256];
  __shared__ float s_add[256], s_g[256], s_b[256];
  __shared__ float redS[8][16], redQ[8][16], s_mean[16], s_rstd[16];

  #define LKW  asm volatile("s_waitcnt lgkmcnt(0)" ::: "memory")
  #define VMW0 asm volatile("s_waitcnt vmcnt(0)" ::: "memory")

  // wave w stages kk-chunk w of half h: 8 x 1KB rows, uniform LDS dest + lane src
  auto STAGEW = [&](const short* W, int h){
    #pragma unroll
    for (int i = 0; i < 8; i++)
      gload16(W + (size_t)(w*16 + h*8 + i)*512 + lane*8, &wbuf[(w*8 + i)*512]);
  };

  // ===== input projection: h = rf@Wi + bi (B frag-packed direct-global) =====
  float* hst  = (float*)&tst[0][0];   // [16][264] f32
  float* embs = hst + 16*264;         // [8][256]  f32
  float* bis  = embs + 2048;          // [256]     f32
  if (tid < 256) bis[tid] = bi[tid];
  for (int i = tid; i < 2048; i += 512) embs[i] = emb[i];
  f32x4 hacc[2] = {};
  #pragma unroll
  for (int kk = 0; kk < 16; kk++){
    const float* ap = rf + (size_t)(b0 + (lane & 15)) * 512 + kk*32 + dsub;
    float4 a0 = *(const float4*)ap, a1 = *(const float4*)(ap + 4);
    float af[8] = {a0.x,a0.y,a0.z,a0.w,a1.x,a1.y,a1.z,a1.w};
    bf16x8 av = pk8(af);
    #pragma unroll
    for (int nj = 0; nj < 2; nj++){
      bf16x8 bv = *(const bf16x8*)(WiT + (size_t)(kk*16 + w*2 + nj)*512 + lane*8);
      hacc[nj] = __builtin_amdgcn_mfma_f32_16x16x32_bf16(av, bv, hacc[nj], 0, 0, 0);
    }
  }
  __syncthreads();   // bis/embs published
  #pragma unroll
  for (int nj = 0; nj < 2; nj++)
    #pragma unroll
    for (int jj = 0; jj < 4; jj++){
      int m = (lane >> 4)*4 + jj, col = w*32 + nj*16 + (lane & 15);
      hst[m*264 + col] = hacc[nj][jj] + bis[col];
    }
  __syncthreads();   // hst published
  // build xf (A-layout) = bf16(h + bi + emb)
  bf16x8 xf[8];
  {
    int r15 = lane & 15;
    int bt = w*2 + (r15 >> 3), ct = r15 & 7;
    #pragma unroll
    for (int c = 0; c < 8; c++){
      float v8[8];
      #pragma unroll
      for (int e = 0; e < 8; e++){
        int d = dsub + 32*c + e;
        v8[e] = hst[bt*264 + d] + embs[ct*256 + d];
      }
      xf[c] = pk8(v8);
    }
  }

  const unsigned long long MASK64 = 0x02191D69752B857EULL;   // ADJ[n][m] at bit n*8+m

  // ===== layers =====
  #pragma unroll 1
  for (int l = 0; l < 3; ++l){
    __syncthreads();   // hst readers (l==0) / prev-layer tst+wbuf readers drained
    if (tid < 256){
      ckb[tid]   = (short)f2bf(ckv[l*256 + tid]);
      s_add[tid] = cvov[l*256 + tid];
      s_g[tid]   = lng[l*256 + tid];
      s_b[tid]   = lnb[l*256 + tid];
    }
    const short* Wq_ = Wqk + l*65536;   // frag-packed [8 kk][16 ntile][512]
    const short* Wv_ = Wvo + l*65536;
    STAGEW(Wq_, 0);
    VMW0; __syncthreads();   // tables + wbuf(G1 h0) ready

    // ---- GEMM1: T = X @ Wqk (B from wbuf); scores via stash-MFMA ----
    f32x4 sacc = {0.f, 0.f, 0.f, 0.f};
    #pragma unroll
    for (int h = 0; h < 2; h++){
      f32x4 acc[8] = {};
      #pragma unroll
      for (int kk = 0; kk < 8; kk++)
        #pragma unroll
        for (int nj = 0; nj < 8; nj++){
          bf16x8 bv = *(const bf16x8*)&wbuf[(kk*8 + nj)*512 + lane*8];
          acc[nj] = __builtin_amdgcn_mfma_f32_16x16x32_bf16(xf[kk], bv, acc[nj], 0, 0, 0);
        }
      if (h == 0){ __syncthreads(); STAGEW(Wq_, 1); }   // stage h1 under stash work
      #pragma unroll
      for (int nj = 0; nj < 8; nj++)
        #pragma unroll
        for (int jj = 0; jj < 4; jj++){
          int i_ = (lane >> 4)*4 + jj, nl = nj*16 + (lane & 15);
          tst[w][(nl >> 5)*512 + (i_ + 16*((nl >> 3) & 3))*8 + (nl & 7)] = (short)f2bf(acc[nj][jj]);
        }
      LKW; __builtin_amdgcn_sched_barrier(0);
      #pragma unroll
      for (int cl = 0; cl < 4; cl++){
        bf16x8 tf = *(const bf16x8*)&tst[w][cl*512 + lane*8];
        sacc = __builtin_amdgcn_mfma_f32_16x16x32_bf16(tf, xf[h*4 + cl], sacc, 0, 0, 0);
      }
      LKW;   // reads drained before next-half overwrite
      if (h == 0){ VMW0; __syncthreads(); }             // wbuf(G1 h1) ready
    }
    __syncthreads();          // all waves done reading wbuf (G1 h1)
    STAGEW(Wv_, 0);           // stage G2 h0 under softmax/PV

    // ---- skv[m] = X[m].ck ----
    float skv = 0.f;
    #pragma unroll
    for (int c = 0; c < 8; c++){
      bf16x8 cv = *(const bf16x8*)&ckb[c*32 + dsub];
      #pragma unroll
      for (int e = 0; e < 8; e++) skv = fmaf(bfs(xf[c][e]), bfs(cv[e]), skv);
    }
    skv += __shfl_xor(skv, 16); skv += __shfl_xor(skv, 32);

    // ---- softmax (C-layout) -> atn[w] ----
    #pragma unroll
    for (int jj = 0; jj < 4; jj++){
      int i_ = (lane >> 4)*4 + jj, j_ = lane & 15;
      bool ok = (((i_ ^ j_) & 8) == 0) &&
                ((MASK64 >> (((i_ & 7) << 3) | (j_ & 7))) & 1ull);
      float sv = ok ? (sacc[jj] + skv) : -3.0e38f;
      float mx = sv;
      mx = fmaxf(mx, __shfl_xor(mx, 1));
      mx = fmaxf(mx, __shfl_xor(mx, 2));
      mx = fmaxf(mx, __shfl_xor(mx, 4));
      float e = ok ? __expf(sv - mx) : 0.f;
      float sum = e;
      sum += __shfl_xor(sum, 1); sum += __shfl_xor(sum, 2); sum += __shfl_xor(sum, 4);
      atn[w][i_][j_] = e / sum;
    }
    LKW;   // own-wave atn writes -> reads

    // ---- PV: yfrag (A-layout) via shfl from xf ----
    bf16x8 yfrag[8];
    {
      float4 A0 = *(const float4*)&atn[w][lane & 15][lane & 8];
      float4 A1 = *(const float4*)&atn[w][lane & 15][(lane & 8) + 4];
      float am[8] = {A0.x, A0.y, A0.z, A0.w, A1.x, A1.y, A1.z, A1.w};
      #pragma unroll
      for (int c = 0; c < 8; c++){
        float a8[8] = {0,0,0,0,0,0,0,0};
        #pragma unroll
        for (int mi = 0; mi < 8; mi++){
          bf16x8 xs = shfl8(xf[c], (lane & 48) | (lane & 8) | mi);
          #pragma unroll
          for (int e = 0; e < 8; e++) a8[e] = fmaf(am[mi], bfs(xs[e]), a8[e]);
        }
        yfrag[c] = pk8(a8);
      }
    }

    // ---- stash X (A-layout, contiguous b128) -> tst[w]; xf dead until LN-apply ----
    #pragma unroll
    for (int c = 0; c < 8; c++)
      *(bf16x8*)&tst[w][c*512 + lane*8] = xf[c];
    LKW; __builtin_amdgcn_sched_barrier(0);
    VMW0; __syncthreads();    // wbuf(G2 h0) ready

    // ---- GEMM2 + epilogue per half: t = acc + cvo + X_res (from stash, C-layout) ----
    float rs[4] = {0,0,0,0}, rq[4] = {0,0,0,0};
    #pragma unroll
    for (int h = 0; h < 2; h++){
      f32x4 acc[8] = {};
      #pragma unroll
      for (int kk = 0; kk < 8; kk++)
        #pragma unroll
        for (int nj = 0; nj < 8; nj++){
          bf16x8 bv = *(const bf16x8*)&wbuf[(kk*8 + nj)*512 + lane*8];
          acc[nj] = __builtin_amdgcn_mfma_f32_16x16x32_bf16(yfrag[kk], bv, acc[nj], 0, 0, 0);
        }
      if (h == 0){ __syncthreads(); STAGEW(Wv_, 1); }   // stage h1 under epilogue
      #pragma unroll
      for (int nj = 0; nj < 8; nj++){
        int n = h*128 + nj*16 + (lane & 15);
        float sadd = s_add[n];
        #pragma unroll
        for (int jj = 0; jj < 4; jj++){
          int i_ = (lane >> 4)*4 + jj;
          int ad = (n >> 5)*512 + (i_ + 16*((n >> 3) & 3))*8 + (n & 7);
          float t = acc[nj][jj] + sadd + bfs(tst[w][ad]);   // RAW same-lane: dep-ordered
          rs[jj] += t; rq[jj] = fmaf(t, t, rq[jj]);
          tst[w][ad] = (short)f2bf(t);                      // overwrite X slot with t
        }
      }
      if (h == 0){ LKW; VMW0; __syncthreads(); }            // wbuf(G2 h1) ready
    }
    // ---- LN stats -> atn[w] scratch (attn probs dead) ----
    float* stp = &atn[w][0][0];
    #pragma unroll
    for (int jj = 0; jj < 4; jj++){
      float s = rs[jj], q = rq[jj];
      s += __shfl_xor(s, 1); q += __shfl_xor(q, 1);
      s += __shfl_xor(s, 2); q += __shfl_xor(q, 2);
      s += __shfl_xor(s, 4); q += __shfl_xor(q, 4);
      s += __shfl_xor(s, 8); q += __shfl_xor(q, 8);
      if ((lane & 15) == 0){
        int i_ = (lane >> 4)*4 + jj;
        float mn = s * (1.f/256.f);
        float var = q * (1.f/256.f) - mn*mn;
        stp[i_]      = mn;
        stp[16 + i_] = rsqrtf(fmaxf(var, 0.f) + 1e-5f);
      }
    }
    LKW; __builtin_amdgcn_sched_barrier(0);   // t-writes + stp visible within wave
    // ---- LN apply: read t (A-layout contiguous), row stats = row lane&15 ----
    {
      float mn = stp[lane & 15], rr = stp[16 + (lane & 15)];
      #pragma unroll
      for (int c = 0; c < 8; c++){
        bf16x8 tv = *(const bf16x8*)&tst[w][c*512 + lane*8];
        float v8[8];
        #pragma unroll
        for (int e = 0; e < 8; e++){
          int d = c*32 + dsub + e;
          v8[e] = (bfs(tv[e]) - mn) * rr * s_g[d] + s_b[d];
        }
        xf[c] = pk8(v8);
      }
    }
    LKW;   // stash reads drained before next layer reuses tst[w]
  } // layers

  // ===== head: GDP-reduce -> Astage -> GEMM vs frag-packed WpT -> LN -> GELU =====
  __syncthreads();   // tst becomes cross-wave Astage
  short* Ast = &tst[0][0];   // [16][264] bf16
  {
    int c7 = lane & 7;
    float g = (c7 == 0) ? 0.4f : (c7 == 1) ? 0.15f : (c7 == 2) ? 0.12f :
              (c7 == 3) ? 0.1f : (c7 == 4) ? 0.08f : (c7 == 5) ? 0.08f :
              (c7 == 6) ? 0.05f : 0.02f;
    #pragma unroll
    for (int c = 0; c < 8; c++){
      float v8[8];
      #pragma unroll
      for (int e = 0; e < 8; e++){
        float v = g * bfs(xf[c][e]);
        v += __shfl_xor(v, 1); v += __shfl_xor(v, 2); v += __shfl_xor(v, 4);
        v8[e] = v;
      }
      if ((lane & 7) == 0){
        int bt = w*2 + ((lane >> 3) & 1);
        *(bf16x8*)&Ast[bt*264 + dsub + 32*c] = pk8(v8);
      }
    }
  }
  __syncthreads();
  f32x4 ha[2] = {};
  #pragma unroll
  for (int kk = 0; kk < 8; kk++){
    bf16x8 av = *(const bf16x8*)&Ast[(lane & 15)*264 + kk*32 + dsub];
    #pragma unroll
    for (int nj = 0; nj < 2; nj++){
      bf16x8 bv = *(const bf16x8*)(WpT + (size_t)(kk*16 + w*2 + nj)*512 + lane*8);
      ha[nj] = __builtin_amdgcn_mfma_f32_16x16x32_bf16(av, bv, ha[nj], 0, 0, 0);
    }
  }
  #pragma unroll
  for (int jj = 0; jj < 4; jj++){
    float s = 0.f, q = 0.f;
    #pragma unroll
    for (int nj = 0; nj < 2; nj++){
      int cx = w*32 + nj*16 + (lane & 15);
      float t = ha[nj][jj] + bpv[cx];
      ha[nj][jj] = t;
      s += t; q = fmaf(t, t, q);
    }
    s += __shfl_xor(s, 1); q += __shfl_xor(q, 1);
    s += __shfl_xor(s, 2); q += __shfl_xor(q, 2);
    s += __shfl_xor(s, 4); q += __shfl_xor(q, 4);
    s += __shfl_xor(s, 8); q += __shfl_xor(q, 8);
    if ((lane & 15) == 0){
      int rl = (lane >> 4)*4 + jj;
      redS[w][rl] = s; redQ[w][rl] = q;
    }
  }
  __syncthreads();
  if (tid < 16){
    float sm = 0.f, sq = 0.f;
    #pragma unroll
    for (int w2 = 0; w2 < 8; w2++){ sm += redS[w2][tid]; sq += redQ[w2][tid]; }
    float mn = sm * (1.f/256.f);
    float var = sq * (1.f/256.f) - mn*mn;
    s_mean[tid] = mn;
    s_rstd[tid] = rsqrtf(fmaxf(var, 0.f) + 1e-5f);
  }
  __syncthreads();
  #pragma unroll
  for (int jj = 0; jj < 4; jj++){
    int rl = (lane >> 4)*4 + jj;
    float mn = s_mean[rl], rstd = s_rstd[rl];
    #pragma unroll
    for (int nj = 0; nj < 2; nj++){
      int cx = w*32 + nj*16 + (lane & 15);
      float y = (ha[nj][jj] - mn) * rstd * lpg[cx] + lpb[cx];
      outp[(size_t)(b0 + rl)*256 + cx] = 0.5f * y * (1.0f + erff(y * 0.70710678118654752f));
    }
  }
  #undef LKW
  #undef VMW0
}

extern "C" void kernel_launch(void* const* d_in, const int* in_sizes, int n_in,
                              void* d_out, int out_size, void* d_ws, size_t ws_size,
                              hipStream_t stream){
  (void)in_sizes; (void)n_in; (void)out_size; (void)ws_size;
  const float* rf  = (const float*)d_in[0];
  const float* Wi  = (const float*)d_in[1];
  const float* bi  = (const float*)d_in[2];
  const float* emb = (const float*)d_in[3];
  const float* Wq  = (const float*)d_in[4];
  const float* bq  = (const float*)d_in[5];
  const float* Wk  = (const float*)d_in[6];
  const float* bk  = (const float*)d_in[7];
  const float* Wv  = (const float*)d_in[8];
  const float* bv  = (const float*)d_in[9];
  const float* Wo  = (const float*)d_in[10];
  const float* bo  = (const float*)d_in[11];
  const float* lng = (const float*)d_in[12];
  const float* lnb = (const float*)d_in[13];
  const float* Wp  = (const float*)d_in[14];
  const float* bp  = (const float*)d_in[15];
  const float* lpg = (const float*)d_in[16];
  const float* lpb = (const float*)d_in[17];

  char* ws = (char*)d_ws;
  short* Wqb  = (short*)(ws);                      // [3][256][1024] bf16
  short* Wkb  = (short*)(ws + 1572864ull);
  short* Wvb  = (short*)(ws + 3145728ull);
  short* WoTb = (short*)(ws + 4718592ull);         // [3][256][1024]
  short* WiTb = (short*)(ws + 6291456ull);         // [256][512] row-major
  short* WpTb = (short*)(ws + 6553600ull);         // [256][256] row-major
  short* Wqk  = (short*)(ws + 6684672ull);         // [3][256][256] row-major, pre-scaled 1/16
  short* Wvo  = (short*)(ws + 7077888ull);         // [3][256][256] row-major
  float* cqv  = (float*)(ws + 7471104ull);
  float* ckv  = (float*)(ws + 7474176ull);
  float* cvov = (float*)(ws + 7477248ull);
  float* c0v  = (float*)(ws + 7480320ull);
  // frag-packed copies
  short* WqkP = (short*)(ws + 7483392ull);         // [3][8][16][512]
  short* WvoP = (short*)(ws + 7876608ull);         // [3][8][16][512]
  short* WiTP = (short*)(ws + 8269824ull);         // [16][16][512]
  short* WpTP = (short*)(ws + 8531968ull);         // [8][16][512]

  { CvP cv;
    cv.src[0]=Wq; cv.dst[0]=Wqb;
    cv.src[1]=Wk; cv.dst[1]=Wkb;
    cv.src[2]=Wv; cv.dst[2]=Wvb;
    cv.src[3]=Wv; cv.dst[3]=Wvb;   // unused slot
    cv.boff[0]=0; cv.boff[1]=384; cv.boff[2]=768; cv.boff[3]=1152; cv.boff[4]=1152;
    k_convert<<<dim3(1152), dim3(256), 0, stream>>>(cv); }

  { TrP tp;
    tp.src[0]=Wi;          tp.dst[0]=WiTb;          tp.rows[0]=512;  tp.cols[0]=256;
    tp.src[1]=Wo;          tp.dst[1]=WoTb;          tp.rows[1]=1024; tp.cols[1]=256;
    tp.src[2]=Wo+262144;   tp.dst[2]=WoTb+262144;   tp.rows[2]=1024; tp.cols[2]=256;
    tp.src[3]=Wo+524288;   tp.dst[3]=WoTb+524288;   tp.rows[3]=1024; tp.cols[3]=256;
    tp.src[4]=Wp;          tp.dst[4]=WpTb;          tp.rows[4]=256;  tp.cols[4]=256;
    tp.toff[0]=0; tp.toff[1]=32; tp.toff[2]=96; tp.toff[3]=160; tp.toff[4]=224; tp.toff[5]=240;
    k_transpose<<<dim3(240), dim3(256), 0, stream>>>(tp); }

  k_vecs2<<<dim3(4, 3), dim3(256), 0, stream>>>(Wqb, Wkb, WoTb, bq, bk, bv, bo,
                                                cqv, ckv, cvov, c0v);

  { GemmP g{};
    for (int l = 0; l < 3; l++){
      g.d[l]   = GDesc{ Wkb  + l*262144, Wqb + l*262144, Wqk + l*65536, 1024, 0.0625f };
      g.d[3+l] = GDesc{ WoTb + l*262144, Wvb + l*262144, Wvo + l*65536, 1024, 1.0f };
    }
    k_gemm128<<<dim3(2,2,6), dim3(256), 0, stream>>>(g); }

  { RpP rp;
    for (int l = 0; l < 3; l++){
      rp.src[l]   = Wqk + l*65536; rp.dst[l]   = WqkP + l*65536; rp.K[l]   = 256;
      rp.src[3+l] = Wvo + l*65536; rp.dst[3+l] = WvoP + l*65536; rp.K[3+l] = 256;
    }
    rp.src[6] = WiTb; rp.dst[6] = WiTP; rp.K[6] = 512;
    rp.src[7] = WpTb; rp.dst[7] = WpTP; rp.K[7] = 256;
    rp.boff[0]=0; rp.boff[1]=8; rp.boff[2]=16; rp.boff[3]=24; rp.boff[4]=32;
    rp.boff[5]=40; rp.boff[6]=48; rp.boff[7]=64; rp.boff[8]=72;
    k_repack<<<dim3(72), dim3(256), 0, stream>>>(rp); }

  k_net<<<dim3(512), dim3(512), 0, stream>>>(rf, WiTP, bi, emb, WqkP, WvoP,
      ckv, cvov, lng, lnb, WpTP, bp, lpg, lpb, (float*)d_out);
}

// Round 15
// 261.537 us; speedup vs baseline: 1.8045x; 1.0107x over previous
//
#include <hip/hip_runtime.h>
#include <hip/hip_bf16.h>
#include <math.h>

// RegionalGNN: B=8192, NC=8, H=256, HD=1024, L=3.
// R15: slim the per-wave serial phases of k_net (R14 base, 238us, all pipes <30%):
//   (1) xf stays live through GEMM2 (32 packed VGPR; fits: xf+yfrag+acc ~100<124).
//   (2) epilogue = f32 exchange in A-layout: acc scatter-write -> contiguous read
//       -> t = acc+cvo+xf (residual lane-local) -> per-row stats via 2 shfl_xor
//       (no LDS stats trip) -> LN in regs. Removes X-stash + 128 scalar LDS ops
//       + ~3 drains per layer. Numerics identical (stats f32, t rounded once).
//   (3) native __float2bfloat16 converts (m240: compiler handles cvt well).

typedef short bf16x8 __attribute__((ext_vector_type(8)));
typedef float f32x4  __attribute__((ext_vector_type(4)));

__device__ __forceinline__ float bflo(unsigned int u){ return __uint_as_float(u << 16); }
__device__ __forceinline__ float bfhi(unsigned int u){ return __uint_as_float(u & 0xffff0000u); }
__device__ __forceinline__ float bfs(short s){ return __uint_as_float((unsigned int)(unsigned short)s << 16); }
__device__ __forceinline__ unsigned short f2bf(float f){
  __hip_bfloat16 h = __float2bfloat16(f);
  return *reinterpret_cast<unsigned short*>(&h);
}
__device__ __forceinline__ void unpack8(uint4 a, float* o){
  o[0]=bflo(a.x); o[1]=bfhi(a.x); o[2]=bflo(a.y); o[3]=bfhi(a.y);
  o[4]=bflo(a.z); o[5]=bfhi(a.z); o[6]=bflo(a.w); o[7]=bfhi(a.w);
}
__device__ __forceinline__ uint4 pack8(const float* v){
  uint4 r;
  r.x = (unsigned int)f2bf(v[0]) | ((unsigned int)f2bf(v[1]) << 16);
  r.y = (unsigned int)f2bf(v[2]) | ((unsigned int)f2bf(v[3]) << 16);
  r.z = (unsigned int)f2bf(v[4]) | ((unsigned int)f2bf(v[5]) << 16);
  r.w = (unsigned int)f2bf(v[6]) | ((unsigned int)f2bf(v[7]) << 16);
  return r;
}
__device__ __forceinline__ void gload16(const void* g, void* l){
  __builtin_amdgcn_global_load_lds(
      (const __attribute__((address_space(1))) unsigned int*)g,
      (__attribute__((address_space(3))) unsigned int*)l, 16, 0, 0);
}
__device__ __forceinline__ bf16x8 shfl8(bf16x8 v, int src){
  union U { bf16x8 h; int u[4]; };
  U a, r; a.h = v;
  #pragma unroll
  for (int j = 0; j < 4; j++) r.u[j] = __shfl(a.u[j], src);
  return r.h;
}
__device__ __forceinline__ bf16x8 pk8(const float* v){
  bf16x8 r;
  #pragma unroll
  for (int j = 0; j < 8; j++) r[j] = (short)f2bf(v[j]);
  return r;
}

// ---------------- convert f32 -> bf16 (Wq, Wk, Wv) ----------------
struct CvP { const float* src[4]; short* dst[4]; int boff[5]; };
__global__ __launch_bounds__(256) void k_convert(CvP p){
  int bid = blockIdx.x, s = 0;
  while (bid >= p.boff[s+1]) s++;
  size_t e = (size_t)(bid - p.boff[s]) * 2048 + (size_t)threadIdx.x * 8;
  const float* src = p.src[s] + e;
  float4 v0 = *(const float4*)src;
  float4 v1 = *(const float4*)(src + 4);
  float v[8] = {v0.x,v0.y,v0.z,v0.w,v1.x,v1.y,v1.z,v1.w};
  *(uint4*)(p.dst[s] + e) = pack8(v);
}

// ---------------- transpose + convert (Wi, Wo x3, Wp) ----------------
struct TrP { const float* src[5]; short* dst[5]; int rows[5]; int cols[5]; int toff[6]; };
__global__ __launch_bounds__(256) void k_transpose(TrP p){
  __shared__ float tile[64][65];
  int bid = blockIdx.x, s = 0;
  while (bid >= p.toff[s+1]) s++;
  int ti = bid - p.toff[s];
  int cols = p.cols[s], rows = p.rows[s];
  int ntc = cols >> 6;
  int r0 = (ti / ntc) * 64, c0 = (ti % ntc) * 64;
  const float* src = p.src[s];
  int row = threadIdx.x >> 2, jb = (threadIdx.x & 3) * 16;
  #pragma unroll
  for (int j = 0; j < 16; j += 4){
    float4 v = *(const float4*)(src + (size_t)(r0 + row) * cols + c0 + jb + j);
    tile[row][jb+j] = v.x; tile[row][jb+j+1] = v.y; tile[row][jb+j+2] = v.z; tile[row][jb+j+3] = v.w;
  }
  __syncthreads();
  short* dst = p.dst[s];
  float tmp[16];
  #pragma unroll
  for (int j = 0; j < 16; j++) tmp[j] = tile[jb + j][row];
  #pragma unroll
  for (int j = 0; j < 16; j += 8)
    *(uint4*)(dst + (size_t)(c0 + row) * rows + r0 + jb + j) = pack8(&tmp[j]);
}

// ---------------- bias-fold vectors via bf16 row-dots ----------------
__global__ __launch_bounds__(256) void k_vecs2(
    const short* Wqb, const short* Wkb, const short* WoTb,
    const float* bq, const float* bk, const float* bv, const float* bo,
    float* cq, float* ck, float* cvo, float* c0){
  const int job = blockIdx.x, l = blockIdx.y, tid = threadIdx.x;
  __shared__ float sv[1024];
  __shared__ float red[256];
  if (job == 3){
    float pp = 0.f;
    #pragma unroll
    for (int i = 0; i < 4; i++){
      int d = tid*4 + i;
      pp = fmaf(bq[l*1024 + d], bk[l*1024 + d], pp);
    }
    red[tid] = pp; __syncthreads();
    for (int o = 128; o > 0; o >>= 1){ if (tid < o) red[tid] += red[tid + o]; __syncthreads(); }
    if (tid == 0) c0[l] = red[0] * 0.0625f;
    return;
  }
  const short* rows = (job==0 ? Wqb : job==1 ? Wkb : WoTb) + (size_t)l*262144;
  const float* vecg = (job==0 ? bk : job==1 ? bq : bv) + l*1024;
  const float scale = (job == 2) ? 1.0f : 0.0625f;
  for (int i = tid; i < 1024; i += 256) sv[i] = vecg[i];
  __syncthreads();
  const int row = tid >> 3, sub = tid & 7;
  for (int pass = 0; pass < 8; pass++){
    int r = pass*32 + row;
    const short* rp = rows + (size_t)r*1024;
    float acc = 0.f;
    #pragma unroll
    for (int i = 0; i < 16; i++){
      int d = sub*8 + i*64;
      uint4 v = *(const uint4*)(rp + d);
      float f[8]; unpack8(v, f);
      #pragma unroll
      for (int j = 0; j < 8; j++) acc = fmaf(f[j], sv[d + j], acc);
    }
    acc += __shfl_xor(acc, 1); acc += __shfl_xor(acc, 2); acc += __shfl_xor(acc, 4);
    if (sub == 0){
      float o = acc * scale;
      if (job == 2) o += bo[l*256 + r];
      (job==0 ? cq : job==1 ? ck : cvo)[l*256 + r] = o;
    }
  }
}

// ---------------- 128x128 MFMA GEMM (weight precompute only) ----------------
struct GDesc { const short* A; const short* Bt; short* C; int K; float scale; };
struct GemmP { GDesc d[6]; };
__global__ __launch_bounds__(256) void k_gemm128(GemmP p){
  GDesc g = p.d[blockIdx.z];
  const int tid = threadIdx.x, lane = tid & 63, w = tid >> 6;
  const int wm = w >> 1, wn = w & 1;
  __shared__ alignas(16) short As[128*32];
  __shared__ alignas(16) short Bs[128*32];
  const int K = g.K;
  const short* Ab = g.A + (size_t)blockIdx.x * 128 * K;
  const short* Bb = g.Bt + (size_t)blockIdx.y * 128 * K;
  f32x4 acc[4][4] = {};
  for (int k0 = 0; k0 < K; k0 += 32){
    #pragma unroll
    for (int i = 0; i < 2; i++){
      int s = w*2 + i;
      int ro = (s >> 2)*64 + (s & 3)*16 + (lane & 15);
      int co = k0 + (lane >> 4) * 8;
      gload16(Ab + (size_t)ro * K + co, &As[s*512]);
      gload16(Bb + (size_t)ro * K + co, &Bs[s*512]);
    }
    __syncthreads();
    bf16x8 av[4], bv[4];
    #pragma unroll
    for (int mi = 0; mi < 4; mi++)
      av[mi] = *(const bf16x8*)&As[((wm*4 + mi)*64 + lane)*8];
    #pragma unroll
    for (int nj = 0; nj < 4; nj++)
      bv[nj] = *(const bf16x8*)&Bs[((wn*4 + nj)*64 + lane)*8];
    #pragma unroll
    for (int mi = 0; mi < 4; mi++)
      #pragma unroll
      for (int nj = 0; nj < 4; nj++)
        acc[mi][nj] = __builtin_amdgcn_mfma_f32_16x16x32_bf16(av[mi], bv[nj], acc[mi][nj], 0, 0, 0);
    __syncthreads();
  }
  const int ldc = gridDim.y * 128;
  #pragma unroll
  for (int mi = 0; mi < 4; mi++)
    #pragma unroll
    for (int nj = 0; nj < 4; nj++){
      int rm0 = blockIdx.x*128 + wm*64 + mi*16 + (lane >> 4) * 4;
      int cn  = blockIdx.y*128 + wn*64 + nj*16 + (lane & 15);
      #pragma unroll
      for (int j = 0; j < 4; j++)
        g.C[(size_t)(rm0 + j) * ldc + cn] = (short)f2bf(acc[mi][nj][j] * g.scale);
    }
}

// ---------------- frag-pack repack: row-major [N][K] -> [(K/32)*16][512] ----------------
struct RpP { const short* src[8]; short* dst[8]; int K[8]; int boff[9]; };
__global__ __launch_bounds__(256) void k_repack(RpP p){
  int bid = blockIdx.x, s = 0;
  while (bid >= p.boff[s+1]) s++;
  int kk = bid - p.boff[s];
  const short* src = p.src[s];
  short* dst = p.dst[s] + (size_t)kk * 8192;
  int K = p.K[s];
  int r15 = threadIdx.x & 15, nt = threadIdx.x >> 4;
  const short* sp = src + (size_t)(nt*16 + r15) * K + kk*32;
  short* dp = dst + nt*512 + r15*8;
  #pragma unroll
  for (int q = 0; q < 4; q++)
    *(uint4*)(dp + q*128) = *(const uint4*)(sp + q*8);
}

// ---------------- mega-kernel: whole network, X in registers, LDS-staged weights ----------------
// Block = 16 batches (128 X-rows), 8 waves. Wave = batch-pair (lane&15 = row).
// xf: A-frag layout, element (r,d) at lane(r + 16*((d>>3)&3)) [d>>3&3 == lane>>4],
// chunk c=d>>5, elem d&7. tst[w] = 8KB multi-use: T-stash (GEMM1) then f32 exchange.
__global__ __launch_bounds__(512, 2) void k_net(
    const float* __restrict__ rf, const short* __restrict__ WiT,
    const float* __restrict__ bi, const float* __restrict__ emb,
    const short* __restrict__ Wqk, const short* __restrict__ Wvo,
    const float* __restrict__ ckv, const float* __restrict__ cvov,
    const float* __restrict__ lng, const float* __restrict__ lnb,
    const short* __restrict__ WpT, const float* __restrict__ bpv,
    const float* __restrict__ lpg, const float* __restrict__ lpb,
    float* __restrict__ outp){
  const int tid = threadIdx.x, lane = tid & 63, w = tid >> 6;
  const int b0 = blockIdx.x * 16;
  const int dsub = (lane >> 4) * 8;
  __shared__ alignas(16) short tst[8][4096];     // 64 KB: per-wave 8KB stash
  __shared__ alignas(16) short wbuf[32768];      // 64 KB: one weight half
  __shared__ alignas(16) float atn[8][16][16];   // 8 KB (attn probs)
  __shared__ short ckb[256];
  __shared__ float s_add[256], s_g[256], s_b[256];
  __shared__ float redS[8][16], redQ[8][16], s_mean[16], s_rstd[16];

  #define LKW  asm volatile("s_waitcnt lgkmcnt(0)" ::: "memory")
  #define VMW0 asm volatile("s_waitcnt vmcnt(0)" ::: "memory")

  auto STAGEW = [&](const short* W, int h){
    #pragma unroll
    for (int i = 0; i < 8; i++)
      gload16(W + (size_t)(w*16 + h*8 + i)*512 + lane*8, &wbuf[(w*8 + i)*512]);
  };

  // ===== input projection: h = rf@Wi + bi (B frag-packed direct-global) =====
  float* hst  = (float*)&tst[0][0];   // [16][264] f32
  float* embs = hst + 16*264;         // [8][256]  f32
  float* bis  = embs + 2048;          // [256]     f32
  if (tid < 256) bis[tid] = bi[tid];
  for (int i = tid; i < 2048; i += 512) embs[i] = emb[i];
  f32x4 hacc[2] = {};
  #pragma unroll
  for (int kk = 0; kk < 16; kk++){
    const float* ap = rf + (size_t)(b0 + (lane & 15)) * 512 + kk*32 + dsub;
    float4 a0 = *(const float4*)ap, a1 = *(const float4*)(ap + 4);
    float af[8] = {a0.x,a0.y,a0.z,a0.w,a1.x,a1.y,a1.z,a1.w};
    bf16x8 av = pk8(af);
    #pragma unroll
    for (int nj = 0; nj < 2; nj++){
      bf16x8 bv = *(const bf16x8*)(WiT + (size_t)(kk*16 + w*2 + nj)*512 + lane*8);
      hacc[nj] = __builtin_amdgcn_mfma_f32_16x16x32_bf16(av, bv, hacc[nj], 0, 0, 0);
    }
  }
  __syncthreads();   // bis/embs published
  #pragma unroll
  for (int nj = 0; nj < 2; nj++)
    #pragma unroll
    for (int jj = 0; jj < 4; jj++){
      int m = (lane >> 4)*4 + jj, col = w*32 + nj*16 + (lane & 15);
      hst[m*264 + col] = hacc[nj][jj] + bis[col];
    }
  __syncthreads();   // hst published
  // build xf (A-layout) = bf16(h + bi + emb)
  bf16x8 xf[8];
  {
    int r15 = lane & 15;
    int bt = w*2 + (r15 >> 3), ct = r15 & 7;
    #pragma unroll
    for (int c = 0; c < 8; c++){
      float v8[8];
      #pragma unroll
      for (int e = 0; e < 8; e++){
        int d = dsub + 32*c + e;
        v8[e] = hst[bt*264 + d] + embs[ct*256 + d];
      }
      xf[c] = pk8(v8);
    }
  }

  const unsigned long long MASK64 = 0x02191D69752B857EULL;   // ADJ[n][m] at bit n*8+m

  // ===== layers =====
  #pragma unroll 1
  for (int l = 0; l < 3; ++l){
    __syncthreads();   // hst readers (l==0) / prev-layer tst+wbuf readers drained
    if (tid < 256){
      ckb[tid]   = (short)f2bf(ckv[l*256 + tid]);
      s_add[tid] = cvov[l*256 + tid];
      s_g[tid]   = lng[l*256 + tid];
      s_b[tid]   = lnb[l*256 + tid];
    }
    const short* Wq_ = Wqk + l*65536;   // frag-packed [8 kk][16 ntile][512]
    const short* Wv_ = Wvo + l*65536;
    STAGEW(Wq_, 0);
    VMW0; __syncthreads();   // tables + wbuf(G1 h0) ready

    // ---- GEMM1: T = X @ Wqk (B from wbuf); scores via stash-MFMA ----
    f32x4 sacc = {0.f, 0.f, 0.f, 0.f};
    #pragma unroll
    for (int h = 0; h < 2; h++){
      f32x4 acc[8] = {};
      #pragma unroll
      for (int kk = 0; kk < 8; kk++)
        #pragma unroll
        for (int nj = 0; nj < 8; nj++){
          bf16x8 bv = *(const bf16x8*)&wbuf[(kk*8 + nj)*512 + lane*8];
          acc[nj] = __builtin_amdgcn_mfma_f32_16x16x32_bf16(xf[kk], bv, acc[nj], 0, 0, 0);
        }
      if (h == 0){ __syncthreads(); STAGEW(Wq_, 1); }   // stage h1 under stash work
      #pragma unroll
      for (int nj = 0; nj < 8; nj++)
        #pragma unroll
        for (int jj = 0; jj < 4; jj++){
          int i_ = (lane >> 4)*4 + jj, nl = nj*16 + (lane & 15);
          tst[w][(nl >> 5)*512 + (i_ + 16*((nl >> 3) & 3))*8 + (nl & 7)] = (short)f2bf(acc[nj][jj]);
        }
      LKW; __builtin_amdgcn_sched_barrier(0);
      #pragma unroll
      for (int cl = 0; cl < 4; cl++){
        bf16x8 tf = *(const bf16x8*)&tst[w][cl*512 + lane*8];
        sacc = __builtin_amdgcn_mfma_f32_16x16x32_bf16(tf, xf[h*4 + cl], sacc, 0, 0, 0);
      }
      LKW;   // reads drained before next-half overwrite
      if (h == 0){ VMW0; __syncthreads(); }             // wbuf(G1 h1) ready
    }
    __syncthreads();          // all waves done reading wbuf (G1 h1)
    STAGEW(Wv_, 0);           // stage G2 h0 under softmax/PV

    // ---- skv[m] = X[m].ck ----
    float skv = 0.f;
    #pragma unroll
    for (int c = 0; c < 8; c++){
      bf16x8 cv = *(const bf16x8*)&ckb[c*32 + dsub];
      #pragma unroll
      for (int e = 0; e < 8; e++) skv = fmaf(bfs(xf[c][e]), bfs(cv[e]), skv);
    }
    skv += __shfl_xor(skv, 16); skv += __shfl_xor(skv, 32);

    // ---- softmax (C-layout) -> atn[w] ----
    #pragma unroll
    for (int jj = 0; jj < 4; jj++){
      int i_ = (lane >> 4)*4 + jj, j_ = lane & 15;
      bool ok = (((i_ ^ j_) & 8) == 0) &&
                ((MASK64 >> (((i_ & 7) << 3) | (j_ & 7))) & 1ull);
      float sv = ok ? (sacc[jj] + skv) : -3.0e38f;
      float mx = sv;
      mx = fmaxf(mx, __shfl_xor(mx, 1));
      mx = fmaxf(mx, __shfl_xor(mx, 2));
      mx = fmaxf(mx, __shfl_xor(mx, 4));
      float e = ok ? __expf(sv - mx) : 0.f;
      float sum = e;
      sum += __shfl_xor(sum, 1); sum += __shfl_xor(sum, 2); sum += __shfl_xor(sum, 4);
      atn[w][i_][j_] = e / sum;
    }
    LKW;   // own-wave atn writes -> reads

    // ---- PV: yfrag (A-layout) via shfl from xf ----
    bf16x8 yfrag[8];
    {
      float4 A0 = *(const float4*)&atn[w][lane & 15][lane & 8];
      float4 A1 = *(const float4*)&atn[w][lane & 15][(lane & 8) + 4];
      float am[8] = {A0.x, A0.y, A0.z, A0.w, A1.x, A1.y, A1.z, A1.w};
      #pragma unroll
      for (int c = 0; c < 8; c++){
        float a8[8] = {0,0,0,0,0,0,0,0};
        #pragma unroll
        for (int mi = 0; mi < 8; mi++){
          bf16x8 xs = shfl8(xf[c], (lane & 48) | (lane & 8) | mi);
          #pragma unroll
          for (int e = 0; e < 8; e++) a8[e] = fmaf(am[mi], bfs(xs[e]), a8[e]);
        }
        yfrag[c] = pk8(a8);
      }
    }
    VMW0; __syncthreads();    // wbuf(G2 h0) ready

    // ---- GEMM2 + epilogue: f32 exchange in A-layout; xf updated in place ----
    float rs = 0.f, rq = 0.f;
    float* fst = (float*)&tst[w][0];    // 2048 floats (one half at a time)
    #pragma unroll
    for (int h = 0; h < 2; h++){
      f32x4 acc[8] = {};
      #pragma unroll
      for (int kk = 0; kk < 8; kk++)
        #pragma unroll
        for (int nj = 0; nj < 8; nj++){
          bf16x8 bv = *(const bf16x8*)&wbuf[(kk*8 + nj)*512 + lane*8];
          acc[nj] = __builtin_amdgcn_mfma_f32_16x16x32_bf16(yfrag[kk], bv, acc[nj], 0, 0, 0);
        }
      if (h == 0){ __syncthreads(); STAGEW(Wv_, 1); }   // stage h1 under exchange
      // scatter acc -> fst (A-layout index over local col d' = n - h*128)
      #pragma unroll
      for (int nj = 0; nj < 8; nj++)
        #pragma unroll
        for (int jj = 0; jj < 4; jj++){
          int i_ = (lane >> 4)*4 + jj;
          int dq = nj*16 + (lane & 15);     // local col 0..127
          fst[(dq >> 5)*512 + (i_ + 16*((dq >> 3) & 3))*8 + (dq & 7)] = acc[nj][jj];
        }
      LKW; __builtin_amdgcn_sched_barrier(0);
      // read back contiguous; t = acc + cvo + residual(xf); stats; xf <- bf16(t)
      #pragma unroll
      for (int lc = 0; lc < 4; lc++){
        int c = h*4 + lc;
        float v8[8];
        #pragma unroll
        for (int e = 0; e < 8; e++){
          int d = 32*c + dsub + e;
          float t = fst[lc*512 + lane*8 + e] + s_add[d] + bfs(xf[c][e]);
          rs += t; rq = fmaf(t, t, rq);
          v8[e] = t;
        }
        xf[c] = pk8(v8);
      }
      LKW;   // reads drained before h1 overwrites fst (and before next layer)
      if (h == 0){ VMW0; __syncthreads(); }             // wbuf(G2 h1) ready
    }
    // ---- per-row LN stats: lane-local + cross-quadrant shfl ----
    rs += __shfl_xor(rs, 16); rs += __shfl_xor(rs, 32);
    rq += __shfl_xor(rq, 16); rq += __shfl_xor(rq, 32);
    float mn = rs * (1.f/256.f);
    float var = rq * (1.f/256.f) - mn*mn;
    float rr = rsqrtf(fmaxf(var, 0.f) + 1e-5f);
    // ---- LN apply in registers ----
    #pragma unroll
    for (int c = 0; c < 8; c++){
      float v8[8];
      #pragma unroll
      for (int e = 0; e < 8; e++){
        int d = 32*c + dsub + e;
        v8[e] = (bfs(xf[c][e]) - mn) * rr * s_g[d] + s_b[d];
      }
      xf[c] = pk8(v8);
    }
  } // layers

  // ===== head: GDP-reduce -> Astage -> GEMM vs frag-packed WpT -> LN -> GELU =====
  __syncthreads();   // tst becomes cross-wave Astage
  short* Ast = &tst[0][0];   // [16][264] bf16
  {
    int c7 = lane & 7;
    float g = (c7 == 0) ? 0.4f : (c7 == 1) ? 0.15f : (c7 == 2) ? 0.12f :
              (c7 == 3) ? 0.1f : (c7 == 4) ? 0.08f : (c7 == 5) ? 0.08f :
              (c7 == 6) ? 0.05f : 0.02f;
    #pragma unroll
    for (int c = 0; c < 8; c++){
      float v8[8];
      #pragma unroll
      for (int e = 0; e < 8; e++){
        float v = g * bfs(xf[c][e]);
        v += __shfl_xor(v, 1); v += __shfl_xor(v, 2); v += __shfl_xor(v, 4);
        v8[e] = v;
      }
      if ((lane & 7) == 0){
        int bt = w*2 + ((lane >> 3) & 1);
        *(bf16x8*)&Ast[bt*264 + dsub + 32*c] = pk8(v8);
      }
    }
  }
  __syncthreads();
  f32x4 ha[2] = {};
  #pragma unroll
  for (int kk = 0; kk < 8; kk++){
    bf16x8 av = *(const bf16x8*)&Ast[(lane & 15)*264 + kk*32 + dsub];
    #pragma unroll
    for (int nj = 0; nj < 2; nj++){
      bf16x8 bv = *(const bf16x8*)(WpT + (size_t)(kk*16 + w*2 + nj)*512 + lane*8);
      ha[nj] = __builtin_amdgcn_mfma_f32_16x16x32_bf16(av, bv, ha[nj], 0, 0, 0);
    }
  }
  #pragma unroll
  for (int jj = 0; jj < 4; jj++){
    float s = 0.f, q = 0.f;
    #pragma unroll
    for (int nj = 0; nj < 2; nj++){
      int cx = w*32 + nj*16 + (lane & 15);
      float t = ha[nj][jj] + bpv[cx];
      ha[nj][jj] = t;
      s += t; q = fmaf(t, t, q);
    }
    s += __shfl_xor(s, 1); q += __shfl_xor(q, 1);
    s += __shfl_xor(s, 2); q += __shfl_xor(q, 2);
    s += __shfl_xor(s, 4); q += __shfl_xor(q, 4);
    s += __shfl_xor(s, 8); q += __shfl_xor(q, 8);
    if ((lane & 15) == 0){
      int rl = (lane >> 4)*4 + jj;
      redS[w][rl] = s; redQ[w][rl] = q;
    }
  }
  __syncthreads();
  if (tid < 16){
    float sm = 0.f, sq = 0.f;
    #pragma unroll
    for (int w2 = 0; w2 < 8; w2++){ sm += redS[w2][tid]; sq += redQ[w2][tid]; }
    float mn = sm * (1.f/256.f);
    float var = sq * (1.f/256.f) - mn*mn;
    s_mean[tid] = mn;
    s_rstd[tid] = rsqrtf(fmaxf(var, 0.f) + 1e-5f);
  }
  __syncthreads();
  #pragma unroll
  for (int jj = 0; jj < 4; jj++){
    int rl = (lane >> 4)*4 + jj;
    float mn = s_mean[rl], rstd = s_rstd[rl];
    #pragma unroll
    for (int nj = 0; nj < 2; nj++){
      int cx = w*32 + nj*16 + (lane & 15);
      float y = (ha[nj][jj] - mn) * rstd * lpg[cx] + lpb[cx];
      outp[(size_t)(b0 + rl)*256 + cx] = 0.5f * y * (1.0f + erff(y * 0.70710678118654752f));
    }
  }
  #undef LKW
  #undef VMW0
}

extern "C" void kernel_launch(void* const* d_in, const int* in_sizes, int n_in,
                              void* d_out, int out_size, void* d_ws, size_t ws_size,
                              hipStream_t stream){
  (void)in_sizes; (void)n_in; (void)out_size; (void)ws_size;
  const float* rf  = (const float*)d_in[0];
  const float* Wi  = (const float*)d_in[1];
  const float* bi  = (const float*)d_in[2];
  const float* emb = (const float*)d_in[3];
  const float* Wq  = (const float*)d_in[4];
  const float* bq  = (const float*)d_in[5];
  const float* Wk  = (const float*)d_in[6];
  const float* bk  = (const float*)d_in[7];
  const float* Wv  = (const float*)d_in[8];
  const float* bv  = (const float*)d_in[9];
  const float* Wo  = (const float*)d_in[10];
  const float* bo  = (const float*)d_in[11];
  const float* lng = (const float*)d_in[12];
  const float* lnb = (const float*)d_in[13];
  const float* Wp  = (const float*)d_in[14];
  const float* bp  = (const float*)d_in[15];
  const float* lpg = (const float*)d_in[16];
  const float* lpb = (const float*)d_in[17];

  char* ws = (char*)d_ws;
  short* Wqb  = (short*)(ws);                      // [3][256][1024] bf16
  short* Wkb  = (short*)(ws + 1572864ull);
  short* Wvb  = (short*)(ws + 3145728ull);
  short* WoTb = (short*)(ws + 4718592ull);         // [3][256][1024]
  short* WiTb = (short*)(ws + 6291456ull);         // [256][512] row-major
  short* WpTb = (short*)(ws + 6553600ull);         // [256][256] row-major
  short* Wqk  = (short*)(ws + 6684672ull);         // [3][256][256] row-major, pre-scaled 1/16
  short* Wvo  = (short*)(ws + 7077888ull);         // [3][256][256] row-major
  float* cqv  = (float*)(ws + 7471104ull);
  float* ckv  = (float*)(ws + 7474176ull);
  float* cvov = (float*)(ws + 7477248ull);
  float* c0v  = (float*)(ws + 7480320ull);
  // frag-packed copies
  short* WqkP = (short*)(ws + 7483392ull);         // [3][8][16][512]
  short* WvoP = (short*)(ws + 7876608ull);         // [3][8][16][512]
  short* WiTP = (short*)(ws + 8269824ull);         // [16][16][512]
  short* WpTP = (short*)(ws + 8531968ull);         // [8][16][512]

  { CvP cv;
    cv.src[0]=Wq; cv.dst[0]=Wqb;
    cv.src[1]=Wk; cv.dst[1]=Wkb;
    cv.src[2]=Wv; cv.dst[2]=Wvb;
    cv.src[3]=Wv; cv.dst[3]=Wvb;   // unused slot
    cv.boff[0]=0; cv.boff[1]=384; cv.boff[2]=768; cv.boff[3]=1152; cv.boff[4]=1152;
    k_convert<<<dim3(1152), dim3(256), 0, stream>>>(cv); }

  { TrP tp;
    tp.src[0]=Wi;          tp.dst[0]=WiTb;          tp.rows[0]=512;  tp.cols[0]=256;
    tp.src[1]=Wo;          tp.dst[1]=WoTb;          tp.rows[1]=1024; tp.cols[1]=256;
    tp.src[2]=Wo+262144;   tp.dst[2]=WoTb+262144;   tp.rows[2]=1024; tp.cols[2]=256;
    tp.src[3]=Wo+524288;   tp.dst[3]=WoTb+524288;   tp.rows[3]=1024; tp.cols[3]=256;
    tp.src[4]=Wp;          tp.dst[4]=WpTb;          tp.rows[4]=256;  tp.cols[4]=256;
    tp.toff[0]=0; tp.toff[1]=32; tp.toff[2]=96; tp.toff[3]=160; tp.toff[4]=224; tp.toff[5]=240;
    k_transpose<<<dim3(240), dim3(256), 0, stream>>>(tp); }

  k_vecs2<<<dim3(4, 3), dim3(256), 0, stream>>>(Wqb, Wkb, WoTb, bq, bk, bv, bo,
                                                cqv, ckv, cvov, c0v);

  { GemmP g{};
    for (int l = 0; l < 3; l++){
      g.d[l]   = GDesc{ Wkb  + l*262144, Wqb + l*262144, Wqk + l*65536, 1024, 0.0625f };
      g.d[3+l] = GDesc{ WoTb + l*262144, Wvb + l*262144, Wvo + l*65536, 1024, 1.0f };
    }
    k_gemm128<<<dim3(2,2,6), dim3(256), 0, stream>>>(g); }

  { RpP rp;
    for (int l = 0; l < 3; l++){
      rp.src[l]   = Wqk + l*65536; rp.dst[l]   = WqkP + l*65536; rp.K[l]   = 256;
      rp.src[3+l] = Wvo + l*65536; rp.dst[3+l] = WvoP + l*65536; rp.K[3+l] = 256;
    }
    rp.src[6] = WiTb; rp.dst[6] = WiTP; rp.K[6] = 512;
    rp.src[7] = WpTb; rp.dst[7] = WpTP; rp.K[7] = 256;
    rp.boff[0]=0; rp.boff[1]=8; rp.boff[2]=16; rp.boff[3]=24; rp.boff[4]=32;
    rp.boff[5]=40; rp.boff[6]=48; rp.boff[7]=64; rp.boff[8]=72;
    k_repack<<<dim3(72), dim3(256), 0, stream>>>(rp); }

  k_net<<<dim3(512), dim3(512), 0, stream>>>(rf, WiTP, bi, emb, WqkP, WvoP,
      ckv, cvov, lng, lnb, WpTP, bp, lpg, lpb, (float*)d_out);
}

// Round 16
// 255.636 us; speedup vs baseline: 1.8461x; 1.0231x over previous
//
#include <hip/hip_runtime.h>
#include <hip/hip_bf16.h>
#include <math.h>

// RegionalGNN: B=8192, NC=8, H=256, HD=1024, L=3.
// R16: XOR-swizzle the per-wave stash rows (single change vs R15).
//      R15 counters: conflicts 9.57M because stash scatter writes have
//      bank = (i_*8+e)%32 with i_%4 = jj constant per instruction -> 8-way.
//      g(r,q) = (r+16q) ^ (r>>2) spreads g%4 over all 4 values per
//      instruction (f32 exchange -> 2-way ~ free; bf16 T-stash -> 4-way).
//      Bijective; reads stay 16B-aligned b128 with identical phase stats.

typedef short bf16x8 __attribute__((ext_vector_type(8)));
typedef float f32x4  __attribute__((ext_vector_type(4)));

__device__ __forceinline__ float bflo(unsigned int u){ return __uint_as_float(u << 16); }
__device__ __forceinline__ float bfhi(unsigned int u){ return __uint_as_float(u & 0xffff0000u); }
__device__ __forceinline__ float bfs(short s){ return __uint_as_float((unsigned int)(unsigned short)s << 16); }
__device__ __forceinline__ unsigned short f2bf(float f){
  __hip_bfloat16 h = __float2bfloat16(f);
  return *reinterpret_cast<unsigned short*>(&h);
}
__device__ __forceinline__ int gsw(int r, int q){ return (r + 16*q) ^ (r >> 2); }
__device__ __forceinline__ void unpack8(uint4 a, float* o){
  o[0]=bflo(a.x); o[1]=bfhi(a.x); o[2]=bflo(a.y); o[3]=bfhi(a.y);
  o[4]=bflo(a.z); o[5]=bfhi(a.z); o[6]=bflo(a.w); o[7]=bfhi(a.w);
}
__device__ __forceinline__ uint4 pack8(const float* v){
  uint4 r;
  r.x = (unsigned int)f2bf(v[0]) | ((unsigned int)f2bf(v[1]) << 16);
  r.y = (unsigned int)f2bf(v[2]) | ((unsigned int)f2bf(v[3]) << 16);
  r.z = (unsigned int)f2bf(v[4]) | ((unsigned int)f2bf(v[5]) << 16);
  r.w = (unsigned int)f2bf(v[6]) | ((unsigned int)f2bf(v[7]) << 16);
  return r;
}
__device__ __forceinline__ void gload16(const void* g, void* l){
  __builtin_amdgcn_global_load_lds(
      (const __attribute__((address_space(1))) unsigned int*)g,
      (__attribute__((address_space(3))) unsigned int*)l, 16, 0, 0);
}
__device__ __forceinline__ bf16x8 shfl8(bf16x8 v, int src){
  union U { bf16x8 h; int u[4]; };
  U a, r; a.h = v;
  #pragma unroll
  for (int j = 0; j < 4; j++) r.u[j] = __shfl(a.u[j], src);
  return r.h;
}
__device__ __forceinline__ bf16x8 pk8(const float* v){
  bf16x8 r;
  #pragma unroll
  for (int j = 0; j < 8; j++) r[j] = (short)f2bf(v[j]);
  return r;
}

// ---------------- convert f32 -> bf16 (Wq, Wk, Wv) ----------------
struct CvP { const float* src[4]; short* dst[4]; int boff[5]; };
__global__ __launch_bounds__(256) void k_convert(CvP p){
  int bid = blockIdx.x, s = 0;
  while (bid >= p.boff[s+1]) s++;
  size_t e = (size_t)(bid - p.boff[s]) * 2048 + (size_t)threadIdx.x * 8;
  const float* src = p.src[s] + e;
  float4 v0 = *(const float4*)src;
  float4 v1 = *(const float4*)(src + 4);
  float v[8] = {v0.x,v0.y,v0.z,v0.w,v1.x,v1.y,v1.z,v1.w};
  *(uint4*)(p.dst[s] + e) = pack8(v);
}

// ---------------- transpose + convert (Wi, Wo x3, Wp) ----------------
struct TrP { const float* src[5]; short* dst[5]; int rows[5]; int cols[5]; int toff[6]; };
__global__ __launch_bounds__(256) void k_transpose(TrP p){
  __shared__ float tile[64][65];
  int bid = blockIdx.x, s = 0;
  while (bid >= p.toff[s+1]) s++;
  int ti = bid - p.toff[s];
  int cols = p.cols[s], rows = p.rows[s];
  int ntc = cols >> 6;
  int r0 = (ti / ntc) * 64, c0 = (ti % ntc) * 64;
  const float* src = p.src[s];
  int row = threadIdx.x >> 2, jb = (threadIdx.x & 3) * 16;
  #pragma unroll
  for (int j = 0; j < 16; j += 4){
    float4 v = *(const float4*)(src + (size_t)(r0 + row) * cols + c0 + jb + j);
    tile[row][jb+j] = v.x; tile[row][jb+j+1] = v.y; tile[row][jb+j+2] = v.z; tile[row][jb+j+3] = v.w;
  }
  __syncthreads();
  short* dst = p.dst[s];
  float tmp[16];
  #pragma unroll
  for (int j = 0; j < 16; j++) tmp[j] = tile[jb + j][row];
  #pragma unroll
  for (int j = 0; j < 16; j += 8)
    *(uint4*)(dst + (size_t)(c0 + row) * rows + r0 + jb + j) = pack8(&tmp[j]);
}

// ---------------- bias-fold vectors via bf16 row-dots ----------------
__global__ __launch_bounds__(256) void k_vecs2(
    const short* Wqb, const short* Wkb, const short* WoTb,
    const float* bq, const float* bk, const float* bv, const float* bo,
    float* cq, float* ck, float* cvo, float* c0){
  const int job = blockIdx.x, l = blockIdx.y, tid = threadIdx.x;
  __shared__ float sv[1024];
  __shared__ float red[256];
  if (job == 3){
    float pp = 0.f;
    #pragma unroll
    for (int i = 0; i < 4; i++){
      int d = tid*4 + i;
      pp = fmaf(bq[l*1024 + d], bk[l*1024 + d], pp);
    }
    red[tid] = pp; __syncthreads();
    for (int o = 128; o > 0; o >>= 1){ if (tid < o) red[tid] += red[tid + o]; __syncthreads(); }
    if (tid == 0) c0[l] = red[0] * 0.0625f;
    return;
  }
  const short* rows = (job==0 ? Wqb : job==1 ? Wkb : WoTb) + (size_t)l*262144;
  const float* vecg = (job==0 ? bk : job==1 ? bq : bv) + l*1024;
  const float scale = (job == 2) ? 1.0f : 0.0625f;
  for (int i = tid; i < 1024; i += 256) sv[i] = vecg[i];
  __syncthreads();
  const int row = tid >> 3, sub = tid & 7;
  for (int pass = 0; pass < 8; pass++){
    int r = pass*32 + row;
    const short* rp = rows + (size_t)r*1024;
    float acc = 0.f;
    #pragma unroll
    for (int i = 0; i < 16; i++){
      int d = sub*8 + i*64;
      uint4 v = *(const uint4*)(rp + d);
      float f[8]; unpack8(v, f);
      #pragma unroll
      for (int j = 0; j < 8; j++) acc = fmaf(f[j], sv[d + j], acc);
    }
    acc += __shfl_xor(acc, 1); acc += __shfl_xor(acc, 2); acc += __shfl_xor(acc, 4);
    if (sub == 0){
      float o = acc * scale;
      if (job == 2) o += bo[l*256 + r];
      (job==0 ? cq : job==1 ? ck : cvo)[l*256 + r] = o;
    }
  }
}

// ---------------- 128x128 MFMA GEMM (weight precompute only) ----------------
struct GDesc { const short* A; const short* Bt; short* C; int K; float scale; };
struct GemmP { GDesc d[6]; };
__global__ __launch_bounds__(256) void k_gemm128(GemmP p){
  GDesc g = p.d[blockIdx.z];
  const int tid = threadIdx.x, lane = tid & 63, w = tid >> 6;
  const int wm = w >> 1, wn = w & 1;
  __shared__ alignas(16) short As[128*32];
  __shared__ alignas(16) short Bs[128*32];
  const int K = g.K;
  const short* Ab = g.A + (size_t)blockIdx.x * 128 * K;
  const short* Bb = g.Bt + (size_t)blockIdx.y * 128 * K;
  f32x4 acc[4][4] = {};
  for (int k0 = 0; k0 < K; k0 += 32){
    #pragma unroll
    for (int i = 0; i < 2; i++){
      int s = w*2 + i;
      int ro = (s >> 2)*64 + (s & 3)*16 + (lane & 15);
      int co = k0 + (lane >> 4) * 8;
      gload16(Ab + (size_t)ro * K + co, &As[s*512]);
      gload16(Bb + (size_t)ro * K + co, &Bs[s*512]);
    }
    __syncthreads();
    bf16x8 av[4], bv[4];
    #pragma unroll
    for (int mi = 0; mi < 4; mi++)
      av[mi] = *(const bf16x8*)&As[((wm*4 + mi)*64 + lane)*8];
    #pragma unroll
    for (int nj = 0; nj < 4; nj++)
      bv[nj] = *(const bf16x8*)&Bs[((wn*4 + nj)*64 + lane)*8];
    #pragma unroll
    for (int mi = 0; mi < 4; mi++)
      #pragma unroll
      for (int nj = 0; nj < 4; nj++)
        acc[mi][nj] = __builtin_amdgcn_mfma_f32_16x16x32_bf16(av[mi], bv[nj], acc[mi][nj], 0, 0, 0);
    __syncthreads();
  }
  const int ldc = gridDim.y * 128;
  #pragma unroll
  for (int mi = 0; mi < 4; mi++)
    #pragma unroll
    for (int nj = 0; nj < 4; nj++){
      int rm0 = blockIdx.x*128 + wm*64 + mi*16 + (lane >> 4) * 4;
      int cn  = blockIdx.y*128 + wn*64 + nj*16 + (lane & 15);
      #pragma unroll
      for (int j = 0; j < 4; j++)
        g.C[(size_t)(rm0 + j) * ldc + cn] = (short)f2bf(acc[mi][nj][j] * g.scale);
    }
}

// ---------------- frag-pack repack: row-major [N][K] -> [(K/32)*16][512] ----------------
struct RpP { const short* src[8]; short* dst[8]; int K[8]; int boff[9]; };
__global__ __launch_bounds__(256) void k_repack(RpP p){
  int bid = blockIdx.x, s = 0;
  while (bid >= p.boff[s+1]) s++;
  int kk = bid - p.boff[s];
  const short* src = p.src[s];
  short* dst = p.dst[s] + (size_t)kk * 8192;
  int K = p.K[s];
  int r15 = threadIdx.x & 15, nt = threadIdx.x >> 4;
  const short* sp = src + (size_t)(nt*16 + r15) * K + kk*32;
  short* dp = dst + nt*512 + r15*8;
  #pragma unroll
  for (int q = 0; q < 4; q++)
    *(uint4*)(dp + q*128) = *(const uint4*)(sp + q*8);
}

// ---------------- mega-kernel: whole network, X in registers, LDS-staged weights ----------------
// Block = 16 batches (128 X-rows), 8 waves. Wave = batch-pair (lane&15 = row).
// xf: A-frag layout. tst[w] stash rows XOR-swizzled: g(r,q) = (r+16q)^(r>>2).
__global__ __launch_bounds__(512, 2) void k_net(
    const float* __restrict__ rf, const short* __restrict__ WiT,
    const float* __restrict__ bi, const float* __restrict__ emb,
    const short* __restrict__ Wqk, const short* __restrict__ Wvo,
    const float* __restrict__ ckv, const float* __restrict__ cvov,
    const float* __restrict__ lng, const float* __restrict__ lnb,
    const short* __restrict__ WpT, const float* __restrict__ bpv,
    const float* __restrict__ lpg, const float* __restrict__ lpb,
    float* __restrict__ outp){
  const int tid = threadIdx.x, lane = tid & 63, w = tid >> 6;
  const int b0 = blockIdx.x * 16;
  const int dsub = (lane >> 4) * 8;
  const int glane = gsw(lane & 15, lane >> 4);   // swizzled stash row for reads
  __shared__ alignas(16) short tst[8][4096];     // 64 KB: per-wave 8KB stash
  __shared__ alignas(16) short wbuf[32768];      // 64 KB: one weight half
  __shared__ alignas(16) float atn[8][16][16];   // 8 KB (attn probs)
  __shared__ short ckb[256];
  __shared__ float s_add[256], s_g[256], s_b[256];
  __shared__ float redS[8][16], redQ[8][16], s_mean[16], s_rstd[16];

  #define LKW  asm volatile("s_waitcnt lgkmcnt(0)" ::: "memory")
  #define VMW0 asm volatile("s_waitcnt vmcnt(0)" ::: "memory")

  auto STAGEW = [&](const short* W, int h){
    #pragma unroll
    for (int i = 0; i < 8; i++)
      gload16(W + (size_t)(w*16 + h*8 + i)*512 + lane*8, &wbuf[(w*8 + i)*512]);
  };

  // ===== input projection: h = rf@Wi + bi (B frag-packed direct-global) =====
  float* hst  = (float*)&tst[0][0];   // [16][264] f32
  float* embs = hst + 16*264;         // [8][256]  f32
  float* bis  = embs + 2048;          // [256]     f32
  if (tid < 256) bis[tid] = bi[tid];
  for (int i = tid; i < 2048; i += 512) embs[i] = emb[i];
  f32x4 hacc[2] = {};
  #pragma unroll
  for (int kk = 0; kk < 16; kk++){
    const float* ap = rf + (size_t)(b0 + (lane & 15)) * 512 + kk*32 + dsub;
    float4 a0 = *(const float4*)ap, a1 = *(const float4*)(ap + 4);
    float af[8] = {a0.x,a0.y,a0.z,a0.w,a1.x,a1.y,a1.z,a1.w};
    bf16x8 av = pk8(af);
    #pragma unroll
    for (int nj = 0; nj < 2; nj++){
      bf16x8 bv = *(const bf16x8*)(WiT + (size_t)(kk*16 + w*2 + nj)*512 + lane*8);
      hacc[nj] = __builtin_amdgcn_mfma_f32_16x16x32_bf16(av, bv, hacc[nj], 0, 0, 0);
    }
  }
  __syncthreads();   // bis/embs published
  #pragma unroll
  for (int nj = 0; nj < 2; nj++)
    #pragma unroll
    for (int jj = 0; jj < 4; jj++){
      int m = (lane >> 4)*4 + jj, col = w*32 + nj*16 + (lane & 15);
      hst[m*264 + col] = hacc[nj][jj] + bis[col];
    }
  __syncthreads();   // hst published
  // build xf (A-layout) = bf16(h + bi + emb)
  bf16x8 xf[8];
  {
    int r15 = lane & 15;
    int bt = w*2 + (r15 >> 3), ct = r15 & 7;
    #pragma unroll
    for (int c = 0; c < 8; c++){
      float v8[8];
      #pragma unroll
      for (int e = 0; e < 8; e++){
        int d = dsub + 32*c + e;
        v8[e] = hst[bt*264 + d] + embs[ct*256 + d];
      }
      xf[c] = pk8(v8);
    }
  }

  const unsigned long long MASK64 = 0x02191D69752B857EULL;   // ADJ[n][m] at bit n*8+m

  // ===== layers =====
  #pragma unroll 1
  for (int l = 0; l < 3; ++l){
    __syncthreads();   // hst readers (l==0) / prev-layer tst+wbuf readers drained
    if (tid < 256){
      ckb[tid]   = (short)f2bf(ckv[l*256 + tid]);
      s_add[tid] = cvov[l*256 + tid];
      s_g[tid]   = lng[l*256 + tid];
      s_b[tid]   = lnb[l*256 + tid];
    }
    const short* Wq_ = Wqk + l*65536;   // frag-packed [8 kk][16 ntile][512]
    const short* Wv_ = Wvo + l*65536;
    STAGEW(Wq_, 0);
    VMW0; __syncthreads();   // tables + wbuf(G1 h0) ready

    // ---- GEMM1: T = X @ Wqk (B from wbuf); scores via stash-MFMA ----
    f32x4 sacc = {0.f, 0.f, 0.f, 0.f};
    #pragma unroll
    for (int h = 0; h < 2; h++){
      f32x4 acc[8] = {};
      #pragma unroll
      for (int kk = 0; kk < 8; kk++)
        #pragma unroll
        for (int nj = 0; nj < 8; nj++){
          bf16x8 bv = *(const bf16x8*)&wbuf[(kk*8 + nj)*512 + lane*8];
          acc[nj] = __builtin_amdgcn_mfma_f32_16x16x32_bf16(xf[kk], bv, acc[nj], 0, 0, 0);
        }
      if (h == 0){ __syncthreads(); STAGEW(Wq_, 1); }   // stage h1 under stash work
      #pragma unroll
      for (int nj = 0; nj < 8; nj++)
        #pragma unroll
        for (int jj = 0; jj < 4; jj++){
          int i_ = (lane >> 4)*4 + jj, nl = nj*16 + (lane & 15);
          tst[w][(nl >> 5)*512 + gsw(i_, (nl >> 3) & 3)*8 + (nl & 7)] = (short)f2bf(acc[nj][jj]);
        }
      LKW; __builtin_amdgcn_sched_barrier(0);
      #pragma unroll
      for (int cl = 0; cl < 4; cl++){
        bf16x8 tf = *(const bf16x8*)&tst[w][cl*512 + glane*8];
        sacc = __builtin_amdgcn_mfma_f32_16x16x32_bf16(tf, xf[h*4 + cl], sacc, 0, 0, 0);
      }
      LKW;   // reads drained before next-half overwrite
      if (h == 0){ VMW0; __syncthreads(); }             // wbuf(G1 h1) ready
    }
    __syncthreads();          // all waves done reading wbuf (G1 h1)
    STAGEW(Wv_, 0);           // stage G2 h0 under softmax/PV

    // ---- skv[m] = X[m].ck ----
    float skv = 0.f;
    #pragma unroll
    for (int c = 0; c < 8; c++){
      bf16x8 cv = *(const bf16x8*)&ckb[c*32 + dsub];
      #pragma unroll
      for (int e = 0; e < 8; e++) skv = fmaf(bfs(xf[c][e]), bfs(cv[e]), skv);
    }
    skv += __shfl_xor(skv, 16); skv += __shfl_xor(skv, 32);

    // ---- softmax (C-layout) -> atn[w] ----
    #pragma unroll
    for (int jj = 0; jj < 4; jj++){
      int i_ = (lane >> 4)*4 + jj, j_ = lane & 15;
      bool ok = (((i_ ^ j_) & 8) == 0) &&
                ((MASK64 >> (((i_ & 7) << 3) | (j_ & 7))) & 1ull);
      float sv = ok ? (sacc[jj] + skv) : -3.0e38f;
      float mx = sv;
      mx = fmaxf(mx, __shfl_xor(mx, 1));
      mx = fmaxf(mx, __shfl_xor(mx, 2));
      mx = fmaxf(mx, __shfl_xor(mx, 4));
      float e = ok ? __expf(sv - mx) : 0.f;
      float sum = e;
      sum += __shfl_xor(sum, 1); sum += __shfl_xor(sum, 2); sum += __shfl_xor(sum, 4);
      atn[w][i_][j_] = e / sum;
    }
    LKW;   // own-wave atn writes -> reads

    // ---- PV: yfrag (A-layout) via shfl from xf ----
    bf16x8 yfrag[8];
    {
      float4 A0 = *(const float4*)&atn[w][lane & 15][lane & 8];
      float4 A1 = *(const float4*)&atn[w][lane & 15][(lane & 8) + 4];
      float am[8] = {A0.x, A0.y, A0.z, A0.w, A1.x, A1.y, A1.z, A1.w};
      #pragma unroll
      for (int c = 0; c < 8; c++){
        float a8[8] = {0,0,0,0,0,0,0,0};
        #pragma unroll
        for (int mi = 0; mi < 8; mi++){
          bf16x8 xs = shfl8(xf[c], (lane & 48) | (lane & 8) | mi);
          #pragma unroll
          for (int e = 0; e < 8; e++) a8[e] = fmaf(am[mi], bfs(xs[e]), a8[e]);
        }
        yfrag[c] = pk8(a8);
      }
    }
    VMW0; __syncthreads();    // wbuf(G2 h0) ready

    // ---- GEMM2 + epilogue: f32 exchange in A-layout; xf updated in place ----
    float rs = 0.f, rq = 0.f;
    float* fst = (float*)&tst[w][0];    // 2048 floats (one half at a time)
    #pragma unroll
    for (int h = 0; h < 2; h++){
      f32x4 acc[8] = {};
      #pragma unroll
      for (int kk = 0; kk < 8; kk++)
        #pragma unroll
        for (int nj = 0; nj < 8; nj++){
          bf16x8 bv = *(const bf16x8*)&wbuf[(kk*8 + nj)*512 + lane*8];
          acc[nj] = __builtin_amdgcn_mfma_f32_16x16x32_bf16(yfrag[kk], bv, acc[nj], 0, 0, 0);
        }
      if (h == 0){ __syncthreads(); STAGEW(Wv_, 1); }   // stage h1 under exchange
      // scatter acc -> fst (swizzled A-layout over local col dq)
      #pragma unroll
      for (int nj = 0; nj < 8; nj++)
        #pragma unroll
        for (int jj = 0; jj < 4; jj++){
          int i_ = (lane >> 4)*4 + jj;
          int dq = nj*16 + (lane & 15);     // local col 0..127
          fst[(dq >> 5)*512 + gsw(i_, (dq >> 3) & 3)*8 + (dq & 7)] = acc[nj][jj];
        }
      LKW; __builtin_amdgcn_sched_barrier(0);
      // read back contiguous; t = acc + cvo + residual(xf); stats; xf <- bf16(t)
      #pragma unroll
      for (int lc = 0; lc < 4; lc++){
        int c = h*4 + lc;
        float v8[8];
        #pragma unroll
        for (int e = 0; e < 8; e++){
          int d = 32*c + dsub + e;
          float t = fst[lc*512 + glane*8 + e] + s_add[d] + bfs(xf[c][e]);
          rs += t; rq = fmaf(t, t, rq);
          v8[e] = t;
        }
        xf[c] = pk8(v8);
      }
      LKW;   // reads drained before h1 overwrites fst (and before next layer)
      if (h == 0){ VMW0; __syncthreads(); }             // wbuf(G2 h1) ready
    }
    // ---- per-row LN stats: lane-local + cross-quadrant shfl ----
    rs += __shfl_xor(rs, 16); rs += __shfl_xor(rs, 32);
    rq += __shfl_xor(rq, 16); rq += __shfl_xor(rq, 32);
    float mn = rs * (1.f/256.f);
    float var = rq * (1.f/256.f) - mn*mn;
    float rr = rsqrtf(fmaxf(var, 0.f) + 1e-5f);
    // ---- LN apply in registers ----
    #pragma unroll
    for (int c = 0; c < 8; c++){
      float v8[8];
      #pragma unroll
      for (int e = 0; e < 8; e++){
        int d = 32*c + dsub + e;
        v8[e] = (bfs(xf[c][e]) - mn) * rr * s_g[d] + s_b[d];
      }
      xf[c] = pk8(v8);
    }
  } // layers

  // ===== head: GDP-reduce -> Astage -> GEMM vs frag-packed WpT -> LN -> GELU =====
  __syncthreads();   // tst becomes cross-wave Astage
  short* Ast = &tst[0][0];   // [16][264] bf16
  {
    int c7 = lane & 7;
    float g = (c7 == 0) ? 0.4f : (c7 == 1) ? 0.15f : (c7 == 2) ? 0.12f :
              (c7 == 3) ? 0.1f : (c7 == 4) ? 0.08f : (c7 == 5) ? 0.08f :
              (c7 == 6) ? 0.05f : 0.02f;
    #pragma unroll
    for (int c = 0; c < 8; c++){
      float v8[8];
      #pragma unroll
      for (int e = 0; e < 8; e++){
        float v = g * bfs(xf[c][e]);
        v += __shfl_xor(v, 1); v += __shfl_xor(v, 2); v += __shfl_xor(v, 4);
        v8[e] = v;
      }
      if ((lane & 7) == 0){
        int bt = w*2 + ((lane >> 3) & 1);
        *(bf16x8*)&Ast[bt*264 + dsub + 32*c] = pk8(v8);
      }
    }
  }
  __syncthreads();
  f32x4 ha[2] = {};
  #pragma unroll
  for (int kk = 0; kk < 8; kk++){
    bf16x8 av = *(const bf16x8*)&Ast[(lane & 15)*264 + kk*32 + dsub];
    #pragma unroll
    for (int nj = 0; nj < 2; nj++){
      bf16x8 bv = *(const bf16x8*)(WpT + (size_t)(kk*16 + w*2 + nj)*512 + lane*8);
      ha[nj] = __builtin_amdgcn_mfma_f32_16x16x32_bf16(av, bv, ha[nj], 0, 0, 0);
    }
  }
  #pragma unroll
  for (int jj = 0; jj < 4; jj++){
    float s = 0.f, q = 0.f;
    #pragma unroll
    for (int nj = 0; nj < 2; nj++){
      int cx = w*32 + nj*16 + (lane & 15);
      float t = ha[nj][jj] + bpv[cx];
      ha[nj][jj] = t;
      s += t; q = fmaf(t, t, q);
    }
    s += __shfl_xor(s, 1); q += __shfl_xor(q, 1);
    s += __shfl_xor(s, 2); q += __shfl_xor(q, 2);
    s += __shfl_xor(s, 4); q += __shfl_xor(q, 4);
    s += __shfl_xor(s, 8); q += __shfl_xor(q, 8);
    if ((lane & 15) == 0){
      int rl = (lane >> 4)*4 + jj;
      redS[w][rl] = s; redQ[w][rl] = q;
    }
  }
  __syncthreads();
  if (tid < 16){
    float sm = 0.f, sq = 0.f;
    #pragma unroll
    for (int w2 = 0; w2 < 8; w2++){ sm += redS[w2][tid]; sq += redQ[w2][tid]; }
    float mn = sm * (1.f/256.f);
    float var = sq * (1.f/256.f) - mn*mn;
    s_mean[tid] = mn;
    s_rstd[tid] = rsqrtf(fmaxf(var, 0.f) + 1e-5f);
  }
  __syncthreads();
  #pragma unroll
  for (int jj = 0; jj < 4; jj++){
    int rl = (lane >> 4)*4 + jj;
    float mn = s_mean[rl], rstd = s_rstd[rl];
    #pragma unroll
    for (int nj = 0; nj < 2; nj++){
      int cx = w*32 + nj*16 + (lane & 15);
      float y = (ha[nj][jj] - mn) * rstd * lpg[cx] + lpb[cx];
      outp[(size_t)(b0 + rl)*256 + cx] = 0.5f * y * (1.0f + erff(y * 0.70710678118654752f));
    }
  }
  #undef LKW
  #undef VMW0
}

extern "C" void kernel_launch(void* const* d_in, const int* in_sizes, int n_in,
                              void* d_out, int out_size, void* d_ws, size_t ws_size,
                              hipStream_t stream){
  (void)in_sizes; (void)n_in; (void)out_size; (void)ws_size;
  const float* rf  = (const float*)d_in[0];
  const float* Wi  = (const float*)d_in[1];
  const float* bi  = (const float*)d_in[2];
  const float* emb = (const float*)d_in[3];
  const float* Wq  = (const float*)d_in[4];
  const float* bq  = (const float*)d_in[5];
  const float* Wk  = (const float*)d_in[6];
  const float* bk  = (const float*)d_in[7];
  const float* Wv  = (const float*)d_in[8];
  const float* bv  = (const float*)d_in[9];
  const float* Wo  = (const float*)d_in[10];
  const float* bo  = (const float*)d_in[11];
  const float* lng = (const float*)d_in[12];
  const float* lnb = (const float*)d_in[13];
  const float* Wp  = (const float*)d_in[14];
  const float* bp  = (const float*)d_in[15];
  const float* lpg = (const float*)d_in[16];
  const float* lpb = (const float*)d_in[17];

  char* ws = (char*)d_ws;
  short* Wqb  = (short*)(ws);                      // [3][256][1024] bf16
  short* Wkb  = (short*)(ws + 1572864ull);
  short* Wvb  = (short*)(ws + 3145728ull);
  short* WoTb = (short*)(ws + 4718592ull);         // [3][256][1024]
  short* WiTb = (short*)(ws + 6291456ull);         // [256][512] row-major
  short* WpTb = (short*)(ws + 6553600ull);         // [256][256] row-major
  short* Wqk  = (short*)(ws + 6684672ull);         // [3][256][256] row-major, pre-scaled 1/16
  short* Wvo  = (short*)(ws + 7077888ull);         // [3][256][256] row-major
  float* cqv  = (float*)(ws + 7471104ull);
  float* ckv  = (float*)(ws + 7474176ull);
  float* cvov = (float*)(ws + 7477248ull);
  float* c0v  = (float*)(ws + 7480320ull);
  // frag-packed copies
  short* WqkP = (short*)(ws + 7483392ull);         // [3][8][16][512]
  short* WvoP = (short*)(ws + 7876608ull);         // [3][8][16][512]
  short* WiTP = (short*)(ws + 8269824ull);         // [16][16][512]
  short* WpTP = (short*)(ws + 8531968ull);         // [8][16][512]

  { CvP cv;
    cv.src[0]=Wq; cv.dst[0]=Wqb;
    cv.src[1]=Wk; cv.dst[1]=Wkb;
    cv.src[2]=Wv; cv.dst[2]=Wvb;
    cv.src[3]=Wv; cv.dst[3]=Wvb;   // unused slot
    cv.boff[0]=0; cv.boff[1]=384; cv.boff[2]=768; cv.boff[3]=1152; cv.boff[4]=1152;
    k_convert<<<dim3(1152), dim3(256), 0, stream>>>(cv); }

  { TrP tp;
    tp.src[0]=Wi;          tp.dst[0]=WiTb;          tp.rows[0]=512;  tp.cols[0]=256;
    tp.src[1]=Wo;          tp.dst[1]=WoTb;          tp.rows[1]=1024; tp.cols[1]=256;
    tp.src[2]=Wo+262144;   tp.dst[2]=WoTb+262144;   tp.rows[2]=1024; tp.cols[2]=256;
    tp.src[3]=Wo+524288;   tp.dst[3]=WoTb+524288;   tp.rows[3]=1024; tp.cols[3]=256;
    tp.src[4]=Wp;          tp.dst[4]=WpTb;          tp.rows[4]=256;  tp.cols[4]=256;
    tp.toff[0]=0; tp.toff[1]=32; tp.toff[2]=96; tp.toff[3]=160; tp.toff[4]=224; tp.toff[5]=240;
    k_transpose<<<dim3(240), dim3(256), 0, stream>>>(tp); }

  k_vecs2<<<dim3(4, 3), dim3(256), 0, stream>>>(Wqb, Wkb, WoTb, bq, bk, bv, bo,
                                                cqv, ckv, cvov, c0v);

  { GemmP g{};
    for (int l = 0; l < 3; l++){
      g.d[l]   = GDesc{ Wkb  + l*262144, Wqb + l*262144, Wqk + l*65536, 1024, 0.0625f };
      g.d[3+l] = GDesc{ WoTb + l*262144, Wvb + l*262144, Wvo + l*65536, 1024, 1.0f };
    }
    k_gemm128<<<dim3(2,2,6), dim3(256), 0, stream>>>(g); }

  { RpP rp;
    for (int l = 0; l < 3; l++){
      rp.src[l]   = Wqk + l*65536; rp.dst[l]   = WqkP + l*65536; rp.K[l]   = 256;
      rp.src[3+l] = Wvo + l*65536; rp.dst[3+l] = WvoP + l*65536; rp.K[3+l] = 256;
    }
    rp.src[6] = WiTb; rp.dst[6] = WiTP; rp.K[6] = 512;
    rp.src[7] = WpTb; rp.dst[7] = WpTP; rp.K[7] = 256;
    rp.boff[0]=0; rp.boff[1]=8; rp.boff[2]=16; rp.boff[3]=24; rp.boff[4]=32;
    rp.boff[5]=40; rp.boff[6]=48; rp.boff[7]=64; rp.boff[8]=72;
    k_repack<<<dim3(72), dim3(256), 0, stream>>>(rp); }

  k_net<<<dim3(512), dim3(512), 0, stream>>>(rf, WiTP, bi, emb, WqkP, WvoP,
      ckv, cvov, lng, lnb, WpTP, bp, lpg, lpb, (float*)d_out);
}

// Round 17
// 206.387 us; speedup vs baseline: 2.2866x; 1.2386x over previous
//
#include <hip/hip_runtime.h>
#include <hip/hip_bf16.h>
#include <math.h>

// RegionalGNN: B=8192, NC=8, H=256, HD=1024, L=3.
// R17: prep-pipeline collapse (k_net untouched from R16, ~208us plateau).
//   Old prep: 5 launches (convert/transpose/vecs2/gemm128@24blk/repack) ~48us.
//   New: k_prep1 (convert + transpose, WiT/WpT written frag-packed directly)
//        k_prep2 (64x64-tile precompute GEMM, K-step 128, grid 96, packed output
//                 + fused ck/cvo bias-fold dots; cq/c0 dead since R6 -> dropped).
//   k_repack eliminated; 2 launches total before k_net.

typedef short bf16x8 __attribute__((ext_vector_type(8)));
typedef float f32x4  __attribute__((ext_vector_type(4)));

__device__ __forceinline__ float bflo(unsigned int u){ return __uint_as_float(u << 16); }
__device__ __forceinline__ float bfhi(unsigned int u){ return __uint_as_float(u & 0xffff0000u); }
__device__ __forceinline__ float bfs(short s){ return __uint_as_float((unsigned int)(unsigned short)s << 16); }
__device__ __forceinline__ unsigned short f2bf(float f){
  __hip_bfloat16 h = __float2bfloat16(f);
  return *reinterpret_cast<unsigned short*>(&h);
}
__device__ __forceinline__ int gsw(int r, int q){ return (r + 16*q) ^ (r >> 2); }
__device__ __forceinline__ void unpack8(uint4 a, float* o){
  o[0]=bflo(a.x); o[1]=bfhi(a.x); o[2]=bflo(a.y); o[3]=bfhi(a.y);
  o[4]=bflo(a.z); o[5]=bfhi(a.z); o[6]=bflo(a.w); o[7]=bfhi(a.w);
}
__device__ __forceinline__ uint4 pack8(const float* v){
  uint4 r;
  r.x = (unsigned int)f2bf(v[0]) | ((unsigned int)f2bf(v[1]) << 16);
  r.y = (unsigned int)f2bf(v[2]) | ((unsigned int)f2bf(v[3]) << 16);
  r.z = (unsigned int)f2bf(v[4]) | ((unsigned int)f2bf(v[5]) << 16);
  r.w = (unsigned int)f2bf(v[6]) | ((unsigned int)f2bf(v[7]) << 16);
  return r;
}
__device__ __forceinline__ void gload16(const void* g, void* l){
  __builtin_amdgcn_global_load_lds(
      (const __attribute__((address_space(1))) unsigned int*)g,
      (__attribute__((address_space(3))) unsigned int*)l, 16, 0, 0);
}
__device__ __forceinline__ bf16x8 shfl8(bf16x8 v, int src){
  union U { bf16x8 h; int u[4]; };
  U a, r; a.h = v;
  #pragma unroll
  for (int j = 0; j < 4; j++) r.u[j] = __shfl(a.u[j], src);
  return r.h;
}
__device__ __forceinline__ bf16x8 pk8(const float* v){
  bf16x8 r;
  #pragma unroll
  for (int j = 0; j < 8; j++) r[j] = (short)f2bf(v[j]);
  return r;
}
// frag-pack index for row-major [N][K] source element (n,k):
__device__ __forceinline__ int pidx(int n, int k){
  return (k >> 5)*8192 + (n >> 4)*512 + ((k >> 3) & 3)*128 + (n & 15)*8 + (k & 7);
}

// ---------------- prep1: convert (Wq,Wk,Wv) + transpose (Wi->packed, Wo x3 row-major, Wp->packed) ----------------
struct P1P {
  const float* csrc[3]; short* cdst[3];
  const float* tsrc[5]; short* tdst[5];
  int trows[5]; int tcols[5]; int tpack[5]; int toff[6];
};
__global__ __launch_bounds__(256) void k_prep1(P1P p){
  __shared__ float tile[64][65];
  int bid = blockIdx.x;
  if (bid < 1152){
    int s = bid / 384, lb = bid % 384;
    size_t e = (size_t)lb * 2048 + (size_t)threadIdx.x * 8;
    const float* src = p.csrc[s] + e;
    float4 v0 = *(const float4*)src;
    float4 v1 = *(const float4*)(src + 4);
    float v[8] = {v0.x,v0.y,v0.z,v0.w,v1.x,v1.y,v1.z,v1.w};
    *(uint4*)(p.cdst[s] + e) = pack8(v);
    return;
  }
  int tb = bid - 1152, s = 0;
  while (tb >= p.toff[s+1]) s++;
  int ti = tb - p.toff[s];
  int cols = p.tcols[s], rows = p.trows[s];
  int ntc = cols >> 6;
  int r0 = (ti / ntc) * 64, c0 = (ti % ntc) * 64;
  const float* src = p.tsrc[s];
  int row = threadIdx.x >> 2, jb = (threadIdx.x & 3) * 16;
  #pragma unroll
  for (int j = 0; j < 16; j += 4){
    float4 v = *(const float4*)(src + (size_t)(r0 + row) * cols + c0 + jb + j);
    tile[row][jb+j] = v.x; tile[row][jb+j+1] = v.y; tile[row][jb+j+2] = v.z; tile[row][jb+j+3] = v.w;
  }
  __syncthreads();
  short* dst = p.tdst[s];
  float tmp[16];
  #pragma unroll
  for (int j = 0; j < 16; j++) tmp[j] = tile[jb + j][row];
  if (p.tpack[s]){
    // output element WT[n][k] = src[k][n]; n = c0+row, k = r0+jb+gq*8+e
    int n = c0 + row;
    #pragma unroll
    for (int gq = 0; gq < 2; gq++){
      int k = r0 + jb + gq*8;
      *(uint4*)(dst + pidx(n, k)) = pack8(&tmp[gq*8]);
    }
  } else {
    #pragma unroll
    for (int j = 0; j < 16; j += 8)
      *(uint4*)(dst + (size_t)(c0 + row) * rows + r0 + jb + j) = pack8(&tmp[j]);
  }
}

// ---------------- prep2: 64x64-tile precompute GEMM (packed output) + ck/cvo dots ----------------
struct GD2 { const short* A; const short* Bt; short* Cp; float scale; };
struct P2P {
  GD2 d[6];
  const short* Wkb; const short* WoTb;
  const float* bq; const float* bv; const float* bo;
  float* ck; float* cvo;
};
__global__ __launch_bounds__(256) void k_prep2(P2P p){
  __shared__ alignas(16) short As[64*128];   // 16 KB
  __shared__ alignas(16) short Bs[64*128];   // 16 KB
  __shared__ float sv[1024];
  const int bid = blockIdx.x, tid = threadIdx.x;
  if (bid < 96){
    const int lane = tid & 63, w = tid >> 6;
    const int wm = w >> 1, wn = w & 1;
    const int z = bid >> 4, rem = bid & 15, bx = rem >> 2, by = rem & 3;
    GD2 g = p.d[z];
    const int K = 1024;
    f32x4 acc[2][2] = {};
    for (int k0 = 0; k0 < K; k0 += 128){
      #pragma unroll
      for (int kc = 0; kc < 4; kc++){
        int ro = w*16 + (lane & 15);
        int co = k0 + kc*32 + (lane >> 4)*8;
        gload16(g.A  + (size_t)(bx*64 + ro)*K + co, &As[(kc*4 + w)*512]);
        gload16(g.Bt + (size_t)(by*64 + ro)*K + co, &Bs[(kc*4 + w)*512]);
      }
      __syncthreads();
      #pragma unroll
      for (int kc = 0; kc < 4; kc++){
        bf16x8 av[2], bv[2];
        #pragma unroll
        for (int mi = 0; mi < 2; mi++)
          av[mi] = *(const bf16x8*)&As[((kc*4 + wm*2 + mi)*64 + lane)*8];
        #pragma unroll
        for (int nj = 0; nj < 2; nj++)
          bv[nj] = *(const bf16x8*)&Bs[((kc*4 + wn*2 + nj)*64 + lane)*8];
        #pragma unroll
        for (int mi = 0; mi < 2; mi++)
          #pragma unroll
          for (int nj = 0; nj < 2; nj++)
            acc[mi][nj] = __builtin_amdgcn_mfma_f32_16x16x32_bf16(av[mi], bv[nj], acc[mi][nj], 0, 0, 0);
      }
      __syncthreads();
    }
    #pragma unroll
    for (int mi = 0; mi < 2; mi++)
      #pragma unroll
      for (int nj = 0; nj < 2; nj++)
        #pragma unroll
        for (int j = 0; j < 4; j++){
          int r = bx*64 + wm*32 + mi*16 + (lane >> 4)*4 + j;
          int c = by*64 + wn*32 + nj*16 + (lane & 15);
          g.Cp[pidx(r, c)] = (short)f2bf(acc[mi][nj][j] * g.scale);
        }
    return;
  }
  // ---- bias-fold dots: v = bid-96; job 0 (v 0..2): ck[l]; job 1 (v 3..5): cvo[l] ----
  int v = bid - 96;
  int job = v / 3, l = v % 3;
  const short* rows = (job == 0 ? p.Wkb : p.WoTb) + (size_t)l*262144;
  const float* vec  = (job == 0 ? p.bq : p.bv) + l*1024;
  const float scale = (job == 0) ? 0.0625f : 1.0f;
  for (int i = tid; i < 1024; i += 256) sv[i] = vec[i];
  __syncthreads();
  const int row = tid >> 3, sub = tid & 7;
  for (int pass = 0; pass < 8; pass++){
    int r = pass*32 + row;
    const short* rp = rows + (size_t)r*1024;
    float acc = 0.f;
    #pragma unroll
    for (int i = 0; i < 16; i++){
      int d = sub*8 + i*64;
      uint4 vv = *(const uint4*)(rp + d);
      float f[8]; unpack8(vv, f);
      #pragma unroll
      for (int j = 0; j < 8; j++) acc = fmaf(f[j], sv[d + j], acc);
    }
    acc += __shfl_xor(acc, 1); acc += __shfl_xor(acc, 2); acc += __shfl_xor(acc, 4);
    if (sub == 0){
      float o = acc * scale;
      if (job == 1) o += p.bo[l*256 + r];
      (job == 0 ? p.ck : p.cvo)[l*256 + r] = o;
    }
  }
}

// ---------------- mega-kernel (unchanged from R16) ----------------
__global__ __launch_bounds__(512, 2) void k_net(
    const float* __restrict__ rf, const short* __restrict__ WiT,
    const float* __restrict__ bi, const float* __restrict__ emb,
    const short* __restrict__ Wqk, const short* __restrict__ Wvo,
    const float* __restrict__ ckv, const float* __restrict__ cvov,
    const float* __restrict__ lng, const float* __restrict__ lnb,
    const short* __restrict__ WpT, const float* __restrict__ bpv,
    const float* __restrict__ lpg, const float* __restrict__ lpb,
    float* __restrict__ outp){
  const int tid = threadIdx.x, lane = tid & 63, w = tid >> 6;
  const int b0 = blockIdx.x * 16;
  const int dsub = (lane >> 4) * 8;
  const int glane = gsw(lane & 15, lane >> 4);
  __shared__ alignas(16) short tst[8][4096];
  __shared__ alignas(16) short wbuf[32768];
  __shared__ alignas(16) float atn[8][16][16];
  __shared__ short ckb[256];
  __shared__ float s_add[256], s_g[256], s_b[256];
  __shared__ float redS[8][16], redQ[8][16], s_mean[16], s_rstd[16];

  #define LKW  asm volatile("s_waitcnt lgkmcnt(0)" ::: "memory")
  #define VMW0 asm volatile("s_waitcnt vmcnt(0)" ::: "memory")

  auto STAGEW = [&](const short* W, int h){
    #pragma unroll
    for (int i = 0; i < 8; i++)
      gload16(W + (size_t)(w*16 + h*8 + i)*512 + lane*8, &wbuf[(w*8 + i)*512]);
  };

  float* hst  = (float*)&tst[0][0];
  float* embs = hst + 16*264;
  float* bis  = embs + 2048;
  if (tid < 256) bis[tid] = bi[tid];
  for (int i = tid; i < 2048; i += 512) embs[i] = emb[i];
  f32x4 hacc[2] = {};
  #pragma unroll
  for (int kk = 0; kk < 16; kk++){
    const float* ap = rf + (size_t)(b0 + (lane & 15)) * 512 + kk*32 + dsub;
    float4 a0 = *(const float4*)ap, a1 = *(const float4*)(ap + 4);
    float af[8] = {a0.x,a0.y,a0.z,a0.w,a1.x,a1.y,a1.z,a1.w};
    bf16x8 av = pk8(af);
    #pragma unroll
    for (int nj = 0; nj < 2; nj++){
      bf16x8 bv = *(const bf16x8*)(WiT + (size_t)(kk*16 + w*2 + nj)*512 + lane*8);
      hacc[nj] = __builtin_amdgcn_mfma_f32_16x16x32_bf16(av, bv, hacc[nj], 0, 0, 0);
    }
  }
  __syncthreads();
  #pragma unroll
  for (int nj = 0; nj < 2; nj++)
    #pragma unroll
    for (int jj = 0; jj < 4; jj++){
      int m = (lane >> 4)*4 + jj, col = w*32 + nj*16 + (lane & 15);
      hst[m*264 + col] = hacc[nj][jj] + bis[col];
    }
  __syncthreads();
  bf16x8 xf[8];
  {
    int r15 = lane & 15;
    int bt = w*2 + (r15 >> 3), ct = r15 & 7;
    #pragma unroll
    for (int c = 0; c < 8; c++){
      float v8[8];
      #pragma unroll
      for (int e = 0; e < 8; e++){
        int d = dsub + 32*c + e;
        v8[e] = hst[bt*264 + d] + embs[ct*256 + d];
      }
      xf[c] = pk8(v8);
    }
  }

  const unsigned long long MASK64 = 0x02191D69752B857EULL;

  #pragma unroll 1
  for (int l = 0; l < 3; ++l){
    __syncthreads();
    if (tid < 256){
      ckb[tid]   = (short)f2bf(ckv[l*256 + tid]);
      s_add[tid] = cvov[l*256 + tid];
      s_g[tid]   = lng[l*256 + tid];
      s_b[tid]   = lnb[l*256 + tid];
    }
    const short* Wq_ = Wqk + l*65536;
    const short* Wv_ = Wvo + l*65536;
    STAGEW(Wq_, 0);
    VMW0; __syncthreads();

    f32x4 sacc = {0.f, 0.f, 0.f, 0.f};
    #pragma unroll
    for (int h = 0; h < 2; h++){
      f32x4 acc[8] = {};
      #pragma unroll
      for (int kk = 0; kk < 8; kk++)
        #pragma unroll
        for (int nj = 0; nj < 8; nj++){
          bf16x8 bv = *(const bf16x8*)&wbuf[(kk*8 + nj)*512 + lane*8];
          acc[nj] = __builtin_amdgcn_mfma_f32_16x16x32_bf16(xf[kk], bv, acc[nj], 0, 0, 0);
        }
      if (h == 0){ __syncthreads(); STAGEW(Wq_, 1); }
      #pragma unroll
      for (int nj = 0; nj < 8; nj++)
        #pragma unroll
        for (int jj = 0; jj < 4; jj++){
          int i_ = (lane >> 4)*4 + jj, nl = nj*16 + (lane & 15);
          tst[w][(nl >> 5)*512 + gsw(i_, (nl >> 3) & 3)*8 + (nl & 7)] = (short)f2bf(acc[nj][jj]);
        }
      LKW; __builtin_amdgcn_sched_barrier(0);
      #pragma unroll
      for (int cl = 0; cl < 4; cl++){
        bf16x8 tf = *(const bf16x8*)&tst[w][cl*512 + glane*8];
        sacc = __builtin_amdgcn_mfma_f32_16x16x32_bf16(tf, xf[h*4 + cl], sacc, 0, 0, 0);
      }
      LKW;
      if (h == 0){ VMW0; __syncthreads(); }
    }
    __syncthreads();
    STAGEW(Wv_, 0);

    float skv = 0.f;
    #pragma unroll
    for (int c = 0; c < 8; c++){
      bf16x8 cv = *(const bf16x8*)&ckb[c*32 + dsub];
      #pragma unroll
      for (int e = 0; e < 8; e++) skv = fmaf(bfs(xf[c][e]), bfs(cv[e]), skv);
    }
    skv += __shfl_xor(skv, 16); skv += __shfl_xor(skv, 32);

    #pragma unroll
    for (int jj = 0; jj < 4; jj++){
      int i_ = (lane >> 4)*4 + jj, j_ = lane & 15;
      bool ok = (((i_ ^ j_) & 8) == 0) &&
                ((MASK64 >> (((i_ & 7) << 3) | (j_ & 7))) & 1ull);
      float sv = ok ? (sacc[jj] + skv) : -3.0e38f;
      float mx = sv;
      mx = fmaxf(mx, __shfl_xor(mx, 1));
      mx = fmaxf(mx, __shfl_xor(mx, 2));
      mx = fmaxf(mx, __shfl_xor(mx, 4));
      float e = ok ? __expf(sv - mx) : 0.f;
      float sum = e;
      sum += __shfl_xor(sum, 1); sum += __shfl_xor(sum, 2); sum += __shfl_xor(sum, 4);
      atn[w][i_][j_] = e / sum;
    }
    LKW;

    bf16x8 yfrag[8];
    {
      float4 A0 = *(const float4*)&atn[w][lane & 15][lane & 8];
      float4 A1 = *(const float4*)&atn[w][lane & 15][(lane & 8) + 4];
      float am[8] = {A0.x, A0.y, A0.z, A0.w, A1.x, A1.y, A1.z, A1.w};
      #pragma unroll
      for (int c = 0; c < 8; c++){
        float a8[8] = {0,0,0,0,0,0,0,0};
        #pragma unroll
        for (int mi = 0; mi < 8; mi++){
          bf16x8 xs = shfl8(xf[c], (lane & 48) | (lane & 8) | mi);
          #pragma unroll
          for (int e = 0; e < 8; e++) a8[e] = fmaf(am[mi], bfs(xs[e]), a8[e]);
        }
        yfrag[c] = pk8(a8);
      }
    }
    VMW0; __syncthreads();

    float rs = 0.f, rq = 0.f;
    float* fst = (float*)&tst[w][0];
    #pragma unroll
    for (int h = 0; h < 2; h++){
      f32x4 acc[8] = {};
      #pragma unroll
      for (int kk = 0; kk < 8; kk++)
        #pragma unroll
        for (int nj = 0; nj < 8; nj++){
          bf16x8 bv = *(const bf16x8*)&wbuf[(kk*8 + nj)*512 + lane*8];
          acc[nj] = __builtin_amdgcn_mfma_f32_16x16x32_bf16(yfrag[kk], bv, acc[nj], 0, 0, 0);
        }
      if (h == 0){ __syncthreads(); STAGEW(Wv_, 1); }
      #pragma unroll
      for (int nj = 0; nj < 8; nj++)
        #pragma unroll
        for (int jj = 0; jj < 4; jj++){
          int i_ = (lane >> 4)*4 + jj;
          int dq = nj*16 + (lane & 15);
          fst[(dq >> 5)*512 + gsw(i_, (dq >> 3) & 3)*8 + (dq & 7)] = acc[nj][jj];
        }
      LKW; __builtin_amdgcn_sched_barrier(0);
      #pragma unroll
      for (int lc = 0; lc < 4; lc++){
        int c = h*4 + lc;
        float v8[8];
        #pragma unroll
        for (int e = 0; e < 8; e++){
          int d = 32*c + dsub + e;
          float t = fst[lc*512 + glane*8 + e] + s_add[d] + bfs(xf[c][e]);
          rs += t; rq = fmaf(t, t, rq);
          v8[e] = t;
        }
        xf[c] = pk8(v8);
      }
      LKW;
      if (h == 0){ VMW0; __syncthreads(); }
    }
    rs += __shfl_xor(rs, 16); rs += __shfl_xor(rs, 32);
    rq += __shfl_xor(rq, 16); rq += __shfl_xor(rq, 32);
    float mn = rs * (1.f/256.f);
    float var = rq * (1.f/256.f) - mn*mn;
    float rr = rsqrtf(fmaxf(var, 0.f) + 1e-5f);
    #pragma unroll
    for (int c = 0; c < 8; c++){
      float v8[8];
      #pragma unroll
      for (int e = 0; e < 8; e++){
        int d = 32*c + dsub + e;
        v8[e] = (bfs(xf[c][e]) - mn) * rr * s_g[d] + s_b[d];
      }
      xf[c] = pk8(v8);
    }
  } // layers

  __syncthreads();
  short* Ast = &tst[0][0];
  {
    int c7 = lane & 7;
    float g = (c7 == 0) ? 0.4f : (c7 == 1) ? 0.15f : (c7 == 2) ? 0.12f :
              (c7 == 3) ? 0.1f : (c7 == 4) ? 0.08f : (c7 == 5) ? 0.08f :
              (c7 == 6) ? 0.05f : 0.02f;
    #pragma unroll
    for (int c = 0; c < 8; c++){
      float v8[8];
      #pragma unroll
      for (int e = 0; e < 8; e++){
        float v = g * bfs(xf[c][e]);
        v += __shfl_xor(v, 1); v += __shfl_xor(v, 2); v += __shfl_xor(v, 4);
        v8[e] = v;
      }
      if ((lane & 7) == 0){
        int bt = w*2 + ((lane >> 3) & 1);
        *(bf16x8*)&Ast[bt*264 + dsub + 32*c] = pk8(v8);
      }
    }
  }
  __syncthreads();
  f32x4 ha[2] = {};
  #pragma unroll
  for (int kk = 0; kk < 8; kk++){
    bf16x8 av = *(const bf16x8*)&Ast[(lane & 15)*264 + kk*32 + dsub];
    #pragma unroll
    for (int nj = 0; nj < 2; nj++){
      bf16x8 bv = *(const bf16x8*)(WpT + (size_t)(kk*16 + w*2 + nj)*512 + lane*8);
      ha[nj] = __builtin_amdgcn_mfma_f32_16x16x32_bf16(av, bv, ha[nj], 0, 0, 0);
    }
  }
  #pragma unroll
  for (int jj = 0; jj < 4; jj++){
    float s = 0.f, q = 0.f;
    #pragma unroll
    for (int nj = 0; nj < 2; nj++){
      int cx = w*32 + nj*16 + (lane & 15);
      float t = ha[nj][jj] + bpv[cx];
      ha[nj][jj] = t;
      s += t; q = fmaf(t, t, q);
    }
    s += __shfl_xor(s, 1); q += __shfl_xor(q, 1);
    s += __shfl_xor(s, 2); q += __shfl_xor(q, 2);
    s += __shfl_xor(s, 4); q += __shfl_xor(q, 4);
    s += __shfl_xor(s, 8); q += __shfl_xor(q, 8);
    if ((lane & 15) == 0){
      int rl = (lane >> 4)*4 + jj;
      redS[w][rl] = s; redQ[w][rl] = q;
    }
  }
  __syncthreads();
  if (tid < 16){
    float sm = 0.f, sq = 0.f;
    #pragma unroll
    for (int w2 = 0; w2 < 8; w2++){ sm += redS[w2][tid]; sq += redQ[w2][tid]; }
    float mn = sm * (1.f/256.f);
    float var = sq * (1.f/256.f) - mn*mn;
    s_mean[tid] = mn;
    s_rstd[tid] = rsqrtf(fmaxf(var, 0.f) + 1e-5f);
  }
  __syncthreads();
  #pragma unroll
  for (int jj = 0; jj < 4; jj++){
    int rl = (lane >> 4)*4 + jj;
    float mn = s_mean[rl], rstd = s_rstd[rl];
    #pragma unroll
    for (int nj = 0; nj < 2; nj++){
      int cx = w*32 + nj*16 + (lane & 15);
      float y = (ha[nj][jj] - mn) * rstd * lpg[cx] + lpb[cx];
      outp[(size_t)(b0 + rl)*256 + cx] = 0.5f * y * (1.0f + erff(y * 0.70710678118654752f));
    }
  }
  #undef LKW
  #undef VMW0
}

extern "C" void kernel_launch(void* const* d_in, const int* in_sizes, int n_in,
                              void* d_out, int out_size, void* d_ws, size_t ws_size,
                              hipStream_t stream){
  (void)in_sizes; (void)n_in; (void)out_size; (void)ws_size;
  const float* rf  = (const float*)d_in[0];
  const float* Wi  = (const float*)d_in[1];
  const float* bi  = (const float*)d_in[2];
  const float* emb = (const float*)d_in[3];
  const float* Wq  = (const float*)d_in[4];
  const float* bq  = (const float*)d_in[5];
  const float* Wk  = (const float*)d_in[6];
  const float* bk  = (const float*)d_in[7];
  const float* Wv  = (const float*)d_in[8];
  const float* bv  = (const float*)d_in[9];
  const float* Wo  = (const float*)d_in[10];
  const float* bo  = (const float*)d_in[11];
  const float* lng = (const float*)d_in[12];
  const float* lnb = (const float*)d_in[13];
  const float* Wp  = (const float*)d_in[14];
  const float* bp  = (const float*)d_in[15];
  const float* lpg = (const float*)d_in[16];
  const float* lpb = (const float*)d_in[17];
  (void)bk;

  char* ws = (char*)d_ws;
  short* Wqb  = (short*)(ws);                      // [3][256][1024] bf16
  short* Wkb  = (short*)(ws + 1572864ull);
  short* Wvb  = (short*)(ws + 3145728ull);
  short* WoTb = (short*)(ws + 4718592ull);         // [3][256][1024] row-major
  short* WqkP = (short*)(ws + 6291456ull);         // [3][8][16][512] packed (scaled 1/16)
  short* WvoP = (short*)(ws + 6684672ull);         // [3][8][16][512] packed
  short* WiTP = (short*)(ws + 7077888ull);         // [16][16][512] packed
  short* WpTP = (short*)(ws + 7340032ull);         // [8][16][512] packed
  float* ckv  = (float*)(ws + 7471104ull);
  float* cvov = (float*)(ws + 7474176ull);

  { P1P p;
    p.csrc[0]=Wq; p.cdst[0]=Wqb;
    p.csrc[1]=Wk; p.cdst[1]=Wkb;
    p.csrc[2]=Wv; p.cdst[2]=Wvb;
    p.tsrc[0]=Wi;        p.tdst[0]=WiTP;          p.trows[0]=512;  p.tcols[0]=256; p.tpack[0]=1;
    p.tsrc[1]=Wo;        p.tdst[1]=WoTb;          p.trows[1]=1024; p.tcols[1]=256; p.tpack[1]=0;
    p.tsrc[2]=Wo+262144; p.tdst[2]=WoTb+262144;   p.trows[2]=1024; p.tcols[2]=256; p.tpack[2]=0;
    p.tsrc[3]=Wo+524288; p.tdst[3]=WoTb+524288;   p.trows[3]=1024; p.tcols[3]=256; p.tpack[3]=0;
    p.tsrc[4]=Wp;        p.tdst[4]=WpTP;          p.trows[4]=256;  p.tcols[4]=256; p.tpack[4]=1;
    p.toff[0]=0; p.toff[1]=32; p.toff[2]=96; p.toff[3]=160; p.toff[4]=224; p.toff[5]=240;
    k_prep1<<<dim3(1392), dim3(256), 0, stream>>>(p); }

  { P2P p;
    for (int l = 0; l < 3; l++){
      p.d[l]   = GD2{ Wkb  + l*262144, Wqb + l*262144, WqkP + l*65536, 0.0625f };
      p.d[3+l] = GD2{ WoTb + l*262144, Wvb + l*262144, WvoP + l*65536, 1.0f };
    }
    p.Wkb = Wkb; p.WoTb = WoTb;
    p.bq = bq; p.bv = bv; p.bo = bo;
    p.ck = ckv; p.cvo = cvov;
    k_prep2<<<dim3(102), dim3(256), 0, stream>>>(p); }

  k_net<<<dim3(512), dim3(512), 0, stream>>>(rf, WiTP, bi, emb, WqkP, WvoP,
      ckv, cvov, lng, lnb, WpTP, bp, lpg, lpb, (float*)d_out);
}